// Round 7
// baseline (190.262 us; speedup 1.0000x reference)
//
#include <hip/hip_runtime.h>
#include <hip/hip_fp16.h>
#include <math.h>

#define Bv   16
#define Nv   256
#define Dv   512
#define Hv   8
#define MNv  4096          // B*N tokens

typedef __attribute__((ext_vector_type(8))) short bf16x8;
typedef __attribute__((ext_vector_type(4))) float f32x4;
typedef __fp16 fp16x8 __attribute__((ext_vector_type(8)));
typedef __fp16 fp16x2 __attribute__((ext_vector_type(2)));

__device__ __forceinline__ unsigned short f2bf(float f) {   // RNE
    unsigned u = __float_as_uint(f);
    u = u + 0x7FFFu + ((u >> 16) & 1u);
    return (unsigned short)(u >> 16);
}
__device__ __forceinline__ void gload_lds16(const void* g, void* l) {
    __builtin_amdgcn_global_load_lds(
        (const __attribute__((address_space(1))) unsigned int*)g,
        (__attribute__((address_space(3))) unsigned int*)l, 16, 0, 0);
}

// ---------------------------------------------------------------------------
// fp32 -> bf16 for the 3 projection inputs (z selects).
// ---------------------------------------------------------------------------
__global__ __launch_bounds__(256) void conv_b16_kernel(
    const float* __restrict__ xq, const float* __restrict__ xk,
    const float* __restrict__ xv, unsigned short* __restrict__ Ab)
{
    const int z = blockIdx.z;
    const float* src = (z == 0) ? xq : (z == 1) ? xk : xv;
    const size_t base = (size_t)z * (MNv * Dv);
    const int idx = (blockIdx.x * 256 + threadIdx.x) * 4;
    float4 x = *(const float4*)(src + idx);
    ushort4 h;
    h.x = f2bf(x.x); h.y = f2bf(x.y); h.z = f2bf(x.z); h.w = f2bf(x.w);
    *(ushort4*)(Ab + base + idx) = h;
}

// ---------------------------------------------------------------------------
// W[k][n] fp32 -> Wt[n][k] bf16 (transposed), all 4 weights (z); also stacks
// the 4 biases into biasStack[z][512].
// ---------------------------------------------------------------------------
__global__ __launch_bounds__(256) void conv_w_kernel(
    const float* __restrict__ Wq, const float* __restrict__ Wk,
    const float* __restrict__ Wv, const float* __restrict__ Wo,
    const float* __restrict__ bq, const float* __restrict__ bk,
    const float* __restrict__ bv, const float* __restrict__ bo,
    unsigned short* __restrict__ Wt, float* __restrict__ biasStack)
{
    const int z = blockIdx.z;
    const float* W = (z == 0) ? Wq : (z == 1) ? Wk : (z == 2) ? Wv : Wo;
    const float* b = (z == 0) ? bq : (z == 1) ? bk : (z == 2) ? bv : bo;
    const int n0 = blockIdx.x * 64, k0 = blockIdx.y * 64;
    const int t = threadIdx.x;
    __shared__ float T[64][65];
    const int col = t & 63, rb = t >> 6;
#pragma unroll
    for (int i = 0; i < 16; ++i) {
        const int row = i * 4 + rb;
        T[row][col] = W[(k0 + row) * Dv + n0 + col];
    }
    __syncthreads();
#pragma unroll
    for (int i = 0; i < 16; ++i) {
        const int row = i * 4 + rb;
        Wt[z * (Dv * Dv) + (n0 + row) * Dv + k0 + col] = f2bf(T[col][row]);
    }
    if (blockIdx.x == 0 && blockIdx.y == 0) {
        biasStack[z * Dv + t]       = b[t];
        biasStack[z * Dv + t + 256] = b[t + 256];
    }
}

// ---------------------------------------------------------------------------
// Fused Q/K/V projection GEMM, one launch, grid (4,32,3) = 384 blocks.
// z=0: Q bf16 row-major scaled 1/8; z=1: K bf16 row-major;
// z=2: V bf16 transposed per-batch [b][d][m].
// ---------------------------------------------------------------------------
__global__ __launch_bounds__(256) void qkv_gemm_kernel(
    const unsigned short* __restrict__ Ab, const unsigned short* __restrict__ Wt,
    const float* __restrict__ bst, unsigned short* __restrict__ Qb2,
    unsigned short* __restrict__ Kb2, unsigned short* __restrict__ Vt2)
{
    const int z = blockIdx.z;
    const unsigned short* A = Ab + (size_t)z * (MNv * Dv);
    const unsigned short* Wz = Wt + (size_t)z * (Dv * Dv);
    const float* bias = bst + z * Dv;

    const int n0 = blockIdx.x * 128;
    const int m0 = blockIdx.y * 128;
    const int t = threadIdx.x;
    const int w = t >> 6, lane = t & 63;
    const int wm = w & 1, wn = w >> 1;

    __shared__ unsigned short As[128][32];
    __shared__ unsigned short Bs[128][32];

    f32x4 acc[4][4] = {};

    const int sr = lane >> 2;
    const int sk = (lane & 3) * 8;
    const int fr = lane & 15;
    const int fk = (lane >> 4) * 8;

    for (int k0 = 0; k0 < Dv; k0 += 32) {
        __syncthreads();
#pragma unroll
        for (int j = 0; j < 2; ++j) {
            const int row = w * 32 + j * 16 + sr;
            gload_lds16(A  + (size_t)(m0 + row) * Dv + k0 + sk, &As[w * 32 + j * 16][0]);
            gload_lds16(Wz + (size_t)(n0 + row) * Dv + k0 + sk, &Bs[w * 32 + j * 16][0]);
        }
        __syncthreads();

        bf16x8 af[4], bfr[4];
#pragma unroll
        for (int mt = 0; mt < 4; ++mt)
            af[mt] = *(const bf16x8*)&As[wm * 64 + mt * 16 + fr][fk];
#pragma unroll
        for (int nt = 0; nt < 4; ++nt)
            bfr[nt] = *(const bf16x8*)&Bs[wn * 64 + nt * 16 + fr][fk];
#pragma unroll
        for (int mt = 0; mt < 4; ++mt)
#pragma unroll
            for (int nt = 0; nt < 4; ++nt)
                acc[mt][nt] = __builtin_amdgcn_mfma_f32_16x16x32_bf16(
                    af[mt], bfr[nt], acc[mt][nt], 0, 0, 0);
    }

    const int er = (lane >> 4) * 4;
    const int ec = lane & 15;
    const float scale = (z == 0) ? 0.125f : 1.0f;
#pragma unroll
    for (int nt = 0; nt < 4; ++nt) {
        const int gn = n0 + wn * 64 + nt * 16 + ec;
        const float bv_ = bias[gn];
#pragma unroll
        for (int mt = 0; mt < 4; ++mt) {
            const int gm = m0 + wm * 64 + mt * 16 + er;
            if (z == 2) {
                ushort4 o;
                o.x = f2bf(acc[mt][nt][0] + bv_);
                o.y = f2bf(acc[mt][nt][1] + bv_);
                o.z = f2bf(acc[mt][nt][2] + bv_);
                o.w = f2bf(acc[mt][nt][3] + bv_);
                *(ushort4*)(Vt2 + ((size_t)(gm >> 8) * Dv + gn) * Nv + (gm & 255)) = o;
            } else {
                unsigned short* cp = ((z == 0) ? Qb2 : Kb2) + (size_t)gm * Dv + gn;
#pragma unroll
                for (int r = 0; r < 4; ++r)
                    cp[(size_t)r * Dv] = f2bf((acc[mt][nt][r] + bv_) * scale);
            }
        }
    }
}

// ---------------------------------------------------------------------------
// Output GEMM: out[4096][512] = CTXb @ Wo^T + bias, fp32.  128x64 tile,
// grid (8,32) = 256 blocks (full GPU).
// ---------------------------------------------------------------------------
__global__ __launch_bounds__(256) void out_gemm_kernel(
    const unsigned short* __restrict__ A, const unsigned short* __restrict__ Wz,
    const float* __restrict__ bias, float* __restrict__ C)
{
    const int n0 = blockIdx.x * 64;
    const int m0 = blockIdx.y * 128;
    const int t = threadIdx.x;
    const int w = t >> 6, lane = t & 63;
    const int wm = w & 1, wn = w >> 1;

    __shared__ unsigned short As[128][32];
    __shared__ unsigned short Bs[64][32];

    f32x4 acc[4][2] = {};

    const int sr = lane >> 2;
    const int sk = (lane & 3) * 8;
    const int fr = lane & 15;
    const int fk = (lane >> 4) * 8;

    for (int k0 = 0; k0 < Dv; k0 += 32) {
        __syncthreads();
#pragma unroll
        for (int j = 0; j < 2; ++j) {
            const int row = w * 32 + j * 16 + sr;
            gload_lds16(A + (size_t)(m0 + row) * Dv + k0 + sk, &As[w * 32 + j * 16][0]);
        }
        gload_lds16(Wz + (size_t)(n0 + w * 16 + sr) * Dv + k0 + sk, &Bs[w * 16][0]);
        __syncthreads();

        bf16x8 af[4], bfr[2];
#pragma unroll
        for (int mt = 0; mt < 4; ++mt)
            af[mt] = *(const bf16x8*)&As[wm * 64 + mt * 16 + fr][fk];
#pragma unroll
        for (int nt = 0; nt < 2; ++nt)
            bfr[nt] = *(const bf16x8*)&Bs[wn * 32 + nt * 16 + fr][fk];
#pragma unroll
        for (int mt = 0; mt < 4; ++mt)
#pragma unroll
            for (int nt = 0; nt < 2; ++nt)
                acc[mt][nt] = __builtin_amdgcn_mfma_f32_16x16x32_bf16(
                    af[mt], bfr[nt], acc[mt][nt], 0, 0, 0);
    }

    const int er = (lane >> 4) * 4;
    const int ec = lane & 15;
#pragma unroll
    for (int nt = 0; nt < 2; ++nt) {
        const int gn = n0 + wn * 32 + nt * 16 + ec;
        const float bv_ = bias[gn];
#pragma unroll
        for (int mt = 0; mt < 4; ++mt) {
            const int gm = m0 + wm * 64 + mt * 16 + er;
            float* cp = C + (size_t)gm * Dv + gn;
#pragma unroll
            for (int r = 0; r < 4; ++r)
                cp[(size_t)r * Dv] = acc[mt][nt][r] + bv_;
        }
    }
}

// ---------------------------------------------------------------------------
// Geometric log-bias via MFMA, v4: hi-only f16 fragments (error budget:
// term err ~1.3e-4, 64-term random walk -> wg err ~1e-3, OK vs 0.028 thr),
// v_cvt_pkrtz packing (2 floats -> half2, 1 instr), 2 MFMAs instead of 6.
// Block=(q,b), 256 thr = 4 waves, no LDS.  LB permuted in m:
// LB[b][h][q][(m&15)*16 + (m>>4)] for attn3's contiguous C-frag init.
// ---------------------------------------------------------------------------
__global__ __launch_bounds__(256) void geo_mfma_kernel(
    const float* __restrict__ box, const int* __restrict__ mask,
    const float* __restrict__ WGw, const float* __restrict__ WGb,
    __half* __restrict__ LB)
{
    const int q = blockIdx.x;
    const int b = blockIdx.y;
    const int t = threadIdx.x;
    const int w = t >> 6, lane = t & 63;
    const int n = lane & 15;
    const int quad = lane >> 4;

    const float4 bq_ = *(const float4*)(box + (b * Nv + q) * 4);
    const float cxq = (bq_.x + bq_.z) * 0.5f;
    const float cyq = (bq_.y + bq_.w) * 0.5f;
    const float wq  = bq_.z - bq_.x + 1.0f;
    const float hq  = bq_.w - bq_.y + 1.0f;

    // B fragments (hi-only f16): sin-weights and cos-weights for head n
    union F16x8 { fp16x8 v; fp16x2 p[4]; };
    F16x8 Bs_, Bc_;
    Bs_.v = (fp16x8){}; Bc_.v = (fp16x8){};
    float bias_n = 0.0f;
    if (n < Hv) {
        bias_n = WGb[n];
#pragma unroll
        for (int jj = 0; jj < 4; ++jj) {
            Bs_.p[jj] = __builtin_amdgcn_cvt_pkrtz(WGw[n * 64 + quad * 8 + 2 * jj],
                                                   WGw[n * 64 + quad * 8 + 2 * jj + 1]);
            Bc_.p[jj] = __builtin_amdgcn_cvt_pkrtz(WGw[n * 64 + 32 + quad * 8 + 2 * jj],
                                                   WGw[n * 64 + 32 + quad * 8 + 2 * jj + 1]);
        }
    }

    const float dimm[8] = {1.0f, 0.42169650342f, 0.17782794100f, 0.07498942093f,
                           0.03162277660f, 0.01333521432f, 0.00562341325f, 0.00237137371f};
    const bool isCtr = (quad < 2);
    const bool isY   = (quad & 1);
    const float cq  = isY ? cyq : cxq;
    const float sq_ = isY ? hq : wq;

#pragma unroll
    for (int i = 0; i < 4; ++i) {
        const int m0 = (w * 4 + i) * 16;
        const float4 bm = *(const float4*)(box + (b * Nv + m0 + n) * 4);
        const float cxm = (bm.x + bm.z) * 0.5f;
        const float cym = (bm.y + bm.w) * 0.5f;
        const float wm  = bm.z - bm.x + 1.0f;
        const float hm  = bm.w - bm.y + 1.0f;
        const float cm_ = isY ? cym : cxm;
        const float sm_ = isY ? hm : wm;
        const float top = isCtr ? fabsf(cq - cm_) : sq_;
        const float bot = isCtr ? sq_ : sm_;
        float r = top / bot;
        if (isCtr) r = fmaxf(r, 1e-3f);
        const float base = 100.0f * __logf(r);

        float sv[8], cv[8];
#pragma unroll
        for (int j = 0; j < 8; ++j)
            __sincosf(base * dimm[j], &sv[j], &cv[j]);

        F16x8 As_, Ac_;
#pragma unroll
        for (int jj = 0; jj < 4; ++jj) {
            As_.p[jj] = __builtin_amdgcn_cvt_pkrtz(sv[2 * jj], sv[2 * jj + 1]);
            Ac_.p[jj] = __builtin_amdgcn_cvt_pkrtz(cv[2 * jj], cv[2 * jj + 1]);
        }

        f32x4 acc = {};
        acc = __builtin_amdgcn_mfma_f32_16x16x32_f16(As_.v, Bs_.v, acc, 0, 0, 0);
        acc = __builtin_amdgcn_mfma_f32_16x16x32_f16(Ac_.v, Bc_.v, acc, 0, 0, 0);

        // epilogue: key m = m0 + quad*4 + rr, head n; permuted pos in m.
        const int mrow = m0 + quad * 4;
        const int4 mk = *(const int4*)(mask + b * Nv + mrow);
        if (n < Hv) {
            const int* mkp = (const int*)&mk;
            unsigned short* dst = (unsigned short*)LB +
                                  ((size_t)(b * Hv + n) * Nv + q) * Nv;
            const int pos0 = quad * 64 + (w * 4 + i);
#pragma unroll
            for (int rr = 0; rr < 4; ++rr) {
                const float val = fmaxf(acc[rr] + bias_n, 1e-6f);
                const float lb = __logf(val) + (mkp[rr] ? 0.0f : -30000.0f);
                dst[pos0 + rr * 16] = __half_as_ushort(__float2half(lb));
            }
        }
    }
}

// ---------------------------------------------------------------------------
// attn3 (MFMA): block=(64q, h, b), 4 waves; wave owns 16 q rows.
// LB (permuted) preloaded as MFMA C accumulator; Q pre-scaled 1/8.
// Softmax in registers; P -> LDS (aliasing dead K); PV vs V^T.
// LDS: Qs 9.2K + Ks/Pb 36.9K + Vt 33.8K = 78K -> 2 blocks/CU.
// ---------------------------------------------------------------------------
__global__ __launch_bounds__(256) void attn3_kernel(
    const unsigned short* __restrict__ Qb2, const unsigned short* __restrict__ Kb2,
    const unsigned short* __restrict__ Vt2, const __half* __restrict__ LB,
    unsigned short* __restrict__ CTXb)
{
    const int qt = blockIdx.x, h = blockIdx.y, b = blockIdx.z;
    const int q0 = qt * 64;
    const int t = threadIdx.x, w = t >> 6, lane = t & 63;
    const int fr = lane & 15, fq = lane >> 4;

    __shared__ unsigned short Qs[64][72];
    __shared__ unsigned short Ks[256][72];
    __shared__ unsigned short Vt[64][264];
    unsigned short (*Pb)[264] = (unsigned short (*)[264])&Ks[0][0];

#pragma unroll
    for (int i = 0; i < 2; ++i) {          // Q
        const int idx = t + i * 256;
        const int row = idx >> 3, cu = idx & 7;
        *(bf16x8*)&Qs[row][cu * 8] =
            *(const bf16x8*)(Qb2 + (size_t)(b * Nv + q0 + row) * Dv + h * 64 + cu * 8);
    }
#pragma unroll
    for (int i = 0; i < 8; ++i) {          // K
        const int idx = t + i * 256;
        const int row = idx >> 3, cu = idx & 7;
        *(bf16x8*)&Ks[row][cu * 8] =
            *(const bf16x8*)(Kb2 + (size_t)(b * Nv + row) * Dv + h * 64 + cu * 8);
    }
#pragma unroll
    for (int i = 0; i < 8; ++i) {          // V^T
        const int idx = t + i * 256;
        const int row = idx >> 5, cu = idx & 31;
        *(bf16x8*)&Vt[row][cu * 8] =
            *(const bf16x8*)(Vt2 + (size_t)b * (Dv * Nv) + (h * 64 + row) * Nv + cu * 8);
    }

    // ---- acc init from permuted LB: row q=qb+r, 16 contiguous halfs @ fr*16
    f32x4 acc[16];
    const int qb = q0 + w * 16 + fq * 4;
    const __half* lbp = LB + ((size_t)(b * Hv + h) * Nv + qb) * Nv + fr * 16;
#pragma unroll
    for (int r = 0; r < 4; ++r) {
        union { int4 v; __half hs[8]; } u0, u1;
        const int4* p = (const int4*)(lbp + (size_t)r * Nv);
        u0.v = p[0]; u1.v = p[1];
#pragma unroll
        for (int nt = 0; nt < 8; ++nt) acc[nt][r]     = __half2float(u0.hs[nt]);
#pragma unroll
        for (int nt = 0; nt < 8; ++nt) acc[nt + 8][r] = __half2float(u1.hs[nt]);
    }

    __syncthreads();

    // ---- QK^T ----
    const bf16x8 aq0 = *(const bf16x8*)&Qs[w * 16 + fr][fq * 8];
    const bf16x8 aq1 = *(const bf16x8*)&Qs[w * 16 + fr][32 + fq * 8];
#pragma unroll
    for (int nt = 0; nt < 16; ++nt) {
        const bf16x8 bk0 = *(const bf16x8*)&Ks[nt * 16 + fr][fq * 8];
        const bf16x8 bk1 = *(const bf16x8*)&Ks[nt * 16 + fr][32 + fq * 8];
        acc[nt] = __builtin_amdgcn_mfma_f32_16x16x32_bf16(aq0, bk0, acc[nt], 0, 0, 0);
        acc[nt] = __builtin_amdgcn_mfma_f32_16x16x32_bf16(aq1, bk1, acc[nt], 0, 0, 0);
    }

    // ---- softmax in registers ----
    float ri[4];
#pragma unroll
    for (int r = 0; r < 4; ++r) {
        float mx = acc[0][r];
#pragma unroll
        for (int nt = 1; nt < 16; ++nt) mx = fmaxf(mx, acc[nt][r]);
        mx = fmaxf(mx, __shfl_xor(mx, 1));
        mx = fmaxf(mx, __shfl_xor(mx, 2));
        mx = fmaxf(mx, __shfl_xor(mx, 4));
        mx = fmaxf(mx, __shfl_xor(mx, 8));
        float s = 0.0f;
#pragma unroll
        for (int nt = 0; nt < 16; ++nt) {
            const float e = __expf(acc[nt][r] - mx);
            acc[nt][r] = e;
            s += e;
        }
        s += __shfl_xor(s, 1);
        s += __shfl_xor(s, 2);
        s += __shfl_xor(s, 4);
        s += __shfl_xor(s, 8);
        ri[r] = 1.0f / s;
    }

    __syncthreads();   // all Ks reads complete before P overwrites the buffer

#pragma unroll
    for (int nt = 0; nt < 16; ++nt)
#pragma unroll
        for (int r = 0; r < 4; ++r)
            Pb[w * 16 + fq * 4 + r][nt * 16 + fr] = f2bf(acc[nt][r] * ri[r]);

    // ---- PV ----
    f32x4 o[4] = {};
#pragma unroll
    for (int kt = 0; kt < 8; ++kt) {
        const bf16x8 ap = *(const bf16x8*)&Pb[w * 16 + fr][kt * 32 + fq * 8];
#pragma unroll
        for (int nt2 = 0; nt2 < 4; ++nt2) {
            const bf16x8 bv_ = *(const bf16x8*)&Vt[nt2 * 16 + fr][kt * 32 + fq * 8];
            o[nt2] = __builtin_amdgcn_mfma_f32_16x16x32_bf16(ap, bv_, o[nt2], 0, 0, 0);
        }
    }

#pragma unroll
    for (int nt2 = 0; nt2 < 4; ++nt2)
#pragma unroll
        for (int r = 0; r < 4; ++r)
            CTXb[(size_t)(b * Nv + qb + r) * Dv + h * 64 + nt2 * 16 + fr] =
                f2bf(o[nt2][r]);
}

// ---------------------------------------------------------------------------
extern "C" void kernel_launch(void* const* d_in, const int* in_sizes, int n_in,
                              void* d_out, int out_size, void* d_ws, size_t ws_size,
                              hipStream_t stream) {
    (void)in_sizes; (void)n_in; (void)out_size; (void)ws_size;

    const float* inq  = (const float*)d_in[0];
    const float* ink  = (const float*)d_in[1];
    const float* inv  = (const float*)d_in[2];
    const float* box  = (const float*)d_in[3];
    const int*   mask = (const int*)d_in[4];
    const float* Wq   = (const float*)d_in[5];
    const float* bq   = (const float*)d_in[6];
    const float* Wk   = (const float*)d_in[7];
    const float* bk   = (const float*)d_in[8];
    const float* Wv   = (const float*)d_in[9];
    const float* bv   = (const float*)d_in[10];
    const float* Wo   = (const float*)d_in[11];
    const float* bo   = (const float*)d_in[12];
    const float* WGw  = (const float*)d_in[13];
    const float* WGb  = (const float*)d_in[14];

    char* W = (char*)d_ws;
    const size_t MB = 1048576;
    unsigned short* Qb2  = (unsigned short*)(W + 0);        // 4 MB bf16 [b][m][512], pre-scaled 1/8
    unsigned short* Kb2  = (unsigned short*)(W + 4 * MB);   // 4 MB bf16 [b][m][512]
    unsigned short* Vt2  = (unsigned short*)(W + 8 * MB);   // 4 MB bf16 [b][d][m]
    unsigned short* Wt   = (unsigned short*)(W + 12 * MB);  // 2 MB (4 transposed weights)
    float*          bst  = (float*)(W + 14 * MB);           // 8 KB bias stack
    unsigned short* CTXb = (unsigned short*)(W + 15 * MB);  // 4 MB
    unsigned short* Ab   = (unsigned short*)(W + 20 * MB);  // 12 MB (3 bf16 input planes)
    __half*         LB   = (__half*)(W + 20 * MB);          // 16.8 MB, aliases Ab (dead after QKV)

    float* out = (float*)d_out;

    conv_b16_kernel<<<dim3(2048, 1, 3), 256, 0, stream>>>(inq, ink, inv, Ab);
    conv_w_kernel<<<dim3(8, 8, 4), 256, 0, stream>>>(Wq, Wk, Wv, Wo, bq, bk, bv, bo, Wt, bst);

    qkv_gemm_kernel<<<dim3(4, 32, 3), 256, 0, stream>>>(Ab, Wt, bst, Qb2, Kb2, Vt2);

    geo_mfma_kernel<<<dim3(Nv, Bv), 256, 0, stream>>>(box, mask, WGw, WGb, LB);

    attn3_kernel<<<dim3(4, 8, 16), 256, 0, stream>>>(Qb2, Kb2, Vt2, LB, CTXb);

    out_gemm_kernel<<<dim3(8, 32), 256, 0, stream>>>(CTXb, Wt + 3 * (Dv * Dv), bst + 3 * Dv, out);
}

// Round 8
// 189.748 us; speedup vs baseline: 1.0027x; 1.0027x over previous
//
#include <hip/hip_runtime.h>
#include <hip/hip_fp16.h>
#include <math.h>

#define Bv   16
#define Nv   256
#define Dv   512
#define Hv   8
#define MNv  4096          // B*N tokens

typedef __attribute__((ext_vector_type(8))) short bf16x8;
typedef __attribute__((ext_vector_type(4))) float f32x4;
typedef __fp16 fp16x8 __attribute__((ext_vector_type(8)));
typedef __fp16 fp16x2 __attribute__((ext_vector_type(2)));

__device__ __forceinline__ unsigned short f2bf(float f) {   // RNE
    unsigned u = __float_as_uint(f);
    u = u + 0x7FFFu + ((u >> 16) & 1u);
    return (unsigned short)(u >> 16);
}
__device__ __forceinline__ void gload_lds16(const void* g, void* l) {
    __builtin_amdgcn_global_load_lds(
        (const __attribute__((address_space(1))) unsigned int*)g,
        (__attribute__((address_space(3))) unsigned int*)l, 16, 0, 0);
}

// HW sin/cos: v_sin_f32/v_cos_f32 take REVOLUTIONS (D=sin(S0*2pi)).
// |x| <= ~700 rad -> |rev| <= ~120; fract reduction err ~5e-5 rad, fine.
__device__ __forceinline__ void fast_sincos(float x, float* s, float* c) {
    const float rev = x * 0.15915494309189535f;   // 1/(2*pi)
    const float fr  = rev - floorf(rev);
    *s = __builtin_amdgcn_sinf(fr);
    *c = __builtin_amdgcn_cosf(fr);
}

// ---------------------------------------------------------------------------
// fp32 -> bf16 for the 3 projection inputs (z selects).
// ---------------------------------------------------------------------------
__global__ __launch_bounds__(256) void conv_b16_kernel(
    const float* __restrict__ xq, const float* __restrict__ xk,
    const float* __restrict__ xv, unsigned short* __restrict__ Ab)
{
    const int z = blockIdx.z;
    const float* src = (z == 0) ? xq : (z == 1) ? xk : xv;
    const size_t base = (size_t)z * (MNv * Dv);
    const int idx = (blockIdx.x * 256 + threadIdx.x) * 4;
    float4 x = *(const float4*)(src + idx);
    ushort4 h;
    h.x = f2bf(x.x); h.y = f2bf(x.y); h.z = f2bf(x.z); h.w = f2bf(x.w);
    *(ushort4*)(Ab + base + idx) = h;
}

// ---------------------------------------------------------------------------
// W[k][n] fp32 -> Wt[n][k] bf16 (transposed), all 4 weights (z); also stacks
// the 4 biases into biasStack[z][512].
// ---------------------------------------------------------------------------
__global__ __launch_bounds__(256) void conv_w_kernel(
    const float* __restrict__ Wq, const float* __restrict__ Wk,
    const float* __restrict__ Wv, const float* __restrict__ Wo,
    const float* __restrict__ bq, const float* __restrict__ bk,
    const float* __restrict__ bv, const float* __restrict__ bo,
    unsigned short* __restrict__ Wt, float* __restrict__ biasStack)
{
    const int z = blockIdx.z;
    const float* W = (z == 0) ? Wq : (z == 1) ? Wk : (z == 2) ? Wv : Wo;
    const float* b = (z == 0) ? bq : (z == 1) ? bk : (z == 2) ? bv : bo;
    const int n0 = blockIdx.x * 64, k0 = blockIdx.y * 64;
    const int t = threadIdx.x;
    __shared__ float T[64][65];
    const int col = t & 63, rb = t >> 6;
#pragma unroll
    for (int i = 0; i < 16; ++i) {
        const int row = i * 4 + rb;
        T[row][col] = W[(k0 + row) * Dv + n0 + col];
    }
    __syncthreads();
#pragma unroll
    for (int i = 0; i < 16; ++i) {
        const int row = i * 4 + rb;
        Wt[z * (Dv * Dv) + (n0 + row) * Dv + k0 + col] = f2bf(T[col][row]);
    }
    if (blockIdx.x == 0 && blockIdx.y == 0) {
        biasStack[z * Dv + t]       = b[t];
        biasStack[z * Dv + t + 256] = b[t + 256];
    }
}

// ---------------------------------------------------------------------------
// Fused Q/K/V projection GEMM, one launch, grid (4,32,3) = 384 blocks.
// z=0: Q bf16 row-major scaled 1/8; z=1: K bf16 row-major;
// z=2: V bf16 transposed per-batch [b][d][m].
// ---------------------------------------------------------------------------
__global__ __launch_bounds__(256) void qkv_gemm_kernel(
    const unsigned short* __restrict__ Ab, const unsigned short* __restrict__ Wt,
    const float* __restrict__ bst, unsigned short* __restrict__ Qb2,
    unsigned short* __restrict__ Kb2, unsigned short* __restrict__ Vt2)
{
    const int z = blockIdx.z;
    const unsigned short* A = Ab + (size_t)z * (MNv * Dv);
    const unsigned short* Wz = Wt + (size_t)z * (Dv * Dv);
    const float* bias = bst + z * Dv;

    const int n0 = blockIdx.x * 128;
    const int m0 = blockIdx.y * 128;
    const int t = threadIdx.x;
    const int w = t >> 6, lane = t & 63;
    const int wm = w & 1, wn = w >> 1;

    __shared__ unsigned short As[128][32];
    __shared__ unsigned short Bs[128][32];

    f32x4 acc[4][4] = {};

    const int sr = lane >> 2;
    const int sk = (lane & 3) * 8;
    const int fr = lane & 15;
    const int fk = (lane >> 4) * 8;

    for (int k0 = 0; k0 < Dv; k0 += 32) {
        __syncthreads();
#pragma unroll
        for (int j = 0; j < 2; ++j) {
            const int row = w * 32 + j * 16 + sr;
            gload_lds16(A  + (size_t)(m0 + row) * Dv + k0 + sk, &As[w * 32 + j * 16][0]);
            gload_lds16(Wz + (size_t)(n0 + row) * Dv + k0 + sk, &Bs[w * 32 + j * 16][0]);
        }
        __syncthreads();

        bf16x8 af[4], bfr[4];
#pragma unroll
        for (int mt = 0; mt < 4; ++mt)
            af[mt] = *(const bf16x8*)&As[wm * 64 + mt * 16 + fr][fk];
#pragma unroll
        for (int nt = 0; nt < 4; ++nt)
            bfr[nt] = *(const bf16x8*)&Bs[wn * 64 + nt * 16 + fr][fk];
#pragma unroll
        for (int mt = 0; mt < 4; ++mt)
#pragma unroll
            for (int nt = 0; nt < 4; ++nt)
                acc[mt][nt] = __builtin_amdgcn_mfma_f32_16x16x32_bf16(
                    af[mt], bfr[nt], acc[mt][nt], 0, 0, 0);
    }

    const int er = (lane >> 4) * 4;
    const int ec = lane & 15;
    const float scale = (z == 0) ? 0.125f : 1.0f;
#pragma unroll
    for (int nt = 0; nt < 4; ++nt) {
        const int gn = n0 + wn * 64 + nt * 16 + ec;
        const float bv_ = bias[gn];
#pragma unroll
        for (int mt = 0; mt < 4; ++mt) {
            const int gm = m0 + wm * 64 + mt * 16 + er;
            if (z == 2) {
                ushort4 o;
                o.x = f2bf(acc[mt][nt][0] + bv_);
                o.y = f2bf(acc[mt][nt][1] + bv_);
                o.z = f2bf(acc[mt][nt][2] + bv_);
                o.w = f2bf(acc[mt][nt][3] + bv_);
                *(ushort4*)(Vt2 + ((size_t)(gm >> 8) * Dv + gn) * Nv + (gm & 255)) = o;
            } else {
                unsigned short* cp = ((z == 0) ? Qb2 : Kb2) + (size_t)gm * Dv + gn;
#pragma unroll
                for (int r = 0; r < 4; ++r)
                    cp[(size_t)r * Dv] = f2bf((acc[mt][nt][r] + bv_) * scale);
            }
        }
    }
}

// ---------------------------------------------------------------------------
// Output GEMM: out[4096][512] = CTXb @ Wo^T + bias, fp32.  128x64 tile,
// grid (8,32) = 256 blocks (full GPU).
// ---------------------------------------------------------------------------
__global__ __launch_bounds__(256) void out_gemm_kernel(
    const unsigned short* __restrict__ A, const unsigned short* __restrict__ Wz,
    const float* __restrict__ bias, float* __restrict__ C)
{
    const int n0 = blockIdx.x * 64;
    const int m0 = blockIdx.y * 128;
    const int t = threadIdx.x;
    const int w = t >> 6, lane = t & 63;
    const int wm = w & 1, wn = w >> 1;

    __shared__ unsigned short As[128][32];
    __shared__ unsigned short Bs[64][32];

    f32x4 acc[4][2] = {};

    const int sr = lane >> 2;
    const int sk = (lane & 3) * 8;
    const int fr = lane & 15;
    const int fk = (lane >> 4) * 8;

    for (int k0 = 0; k0 < Dv; k0 += 32) {
        __syncthreads();
#pragma unroll
        for (int j = 0; j < 2; ++j) {
            const int row = w * 32 + j * 16 + sr;
            gload_lds16(A + (size_t)(m0 + row) * Dv + k0 + sk, &As[w * 32 + j * 16][0]);
        }
        gload_lds16(Wz + (size_t)(n0 + w * 16 + sr) * Dv + k0 + sk, &Bs[w * 16][0]);
        __syncthreads();

        bf16x8 af[4], bfr[2];
#pragma unroll
        for (int mt = 0; mt < 4; ++mt)
            af[mt] = *(const bf16x8*)&As[wm * 64 + mt * 16 + fr][fk];
#pragma unroll
        for (int nt = 0; nt < 2; ++nt)
            bfr[nt] = *(const bf16x8*)&Bs[wn * 32 + nt * 16 + fr][fk];
#pragma unroll
        for (int mt = 0; mt < 4; ++mt)
#pragma unroll
            for (int nt = 0; nt < 2; ++nt)
                acc[mt][nt] = __builtin_amdgcn_mfma_f32_16x16x32_bf16(
                    af[mt], bfr[nt], acc[mt][nt], 0, 0, 0);
    }

    const int er = (lane >> 4) * 4;
    const int ec = lane & 15;
#pragma unroll
    for (int nt = 0; nt < 2; ++nt) {
        const int gn = n0 + wn * 32 + nt * 16 + ec;
        const float bv_ = bias[gn];
#pragma unroll
        for (int mt = 0; mt < 4; ++mt) {
            const int gm = m0 + wm * 64 + mt * 16 + er;
            float* cp = C + (size_t)gm * Dv + gn;
#pragma unroll
            for (int r = 0; r < 4; ++r)
                cp[(size_t)r * Dv] = acc[mt][nt][r] + bv_;
        }
    }
}

// ---------------------------------------------------------------------------
// Geometric log-bias via MFMA, v5: raw HW v_sin/v_cos (fast_sincos) instead
// of OCML __sincosf (~80 instrs/call -> 7).  hi-only f16 fragments, pkrtz
// packing, 2 MFMAs.  Block=(q,b), 256 thr = 4 waves, no LDS.  LB permuted
// in m: LB[b][h][q][(m&15)*16 + (m>>4)] for attn3's contiguous C-frag init.
// ---------------------------------------------------------------------------
__global__ __launch_bounds__(256) void geo_mfma_kernel(
    const float* __restrict__ box, const int* __restrict__ mask,
    const float* __restrict__ WGw, const float* __restrict__ WGb,
    __half* __restrict__ LB)
{
    const int q = blockIdx.x;
    const int b = blockIdx.y;
    const int t = threadIdx.x;
    const int w = t >> 6, lane = t & 63;
    const int n = lane & 15;
    const int quad = lane >> 4;

    const float4 bq_ = *(const float4*)(box + (b * Nv + q) * 4);
    const float cxq = (bq_.x + bq_.z) * 0.5f;
    const float cyq = (bq_.y + bq_.w) * 0.5f;
    const float wq  = bq_.z - bq_.x + 1.0f;
    const float hq  = bq_.w - bq_.y + 1.0f;

    union F16x8 { fp16x8 v; fp16x2 p[4]; };
    F16x8 Bs_, Bc_;
    Bs_.v = (fp16x8){}; Bc_.v = (fp16x8){};
    float bias_n = 0.0f;
    if (n < Hv) {
        bias_n = WGb[n];
#pragma unroll
        for (int jj = 0; jj < 4; ++jj) {
            Bs_.p[jj] = __builtin_amdgcn_cvt_pkrtz(WGw[n * 64 + quad * 8 + 2 * jj],
                                                   WGw[n * 64 + quad * 8 + 2 * jj + 1]);
            Bc_.p[jj] = __builtin_amdgcn_cvt_pkrtz(WGw[n * 64 + 32 + quad * 8 + 2 * jj],
                                                   WGw[n * 64 + 32 + quad * 8 + 2 * jj + 1]);
        }
    }

    const float dimm[8] = {1.0f, 0.42169650342f, 0.17782794100f, 0.07498942093f,
                           0.03162277660f, 0.01333521432f, 0.00562341325f, 0.00237137371f};
    const bool isCtr = (quad < 2);
    const bool isY   = (quad & 1);
    const float cq  = isY ? cyq : cxq;
    const float sq_ = isY ? hq : wq;

#pragma unroll
    for (int i = 0; i < 4; ++i) {
        const int m0 = (w * 4 + i) * 16;
        const float4 bm = *(const float4*)(box + (b * Nv + m0 + n) * 4);
        const float cxm = (bm.x + bm.z) * 0.5f;
        const float cym = (bm.y + bm.w) * 0.5f;
        const float wm  = bm.z - bm.x + 1.0f;
        const float hm  = bm.w - bm.y + 1.0f;
        const float cm_ = isY ? cym : cxm;
        const float sm_ = isY ? hm : wm;
        const float top = isCtr ? fabsf(cq - cm_) : sq_;
        const float bot = isCtr ? sq_ : sm_;
        float r = top / bot;
        if (isCtr) r = fmaxf(r, 1e-3f);
        const float base = 100.0f * __logf(r);

        float sv[8], cv[8];
#pragma unroll
        for (int j = 0; j < 8; ++j)
            fast_sincos(base * dimm[j], &sv[j], &cv[j]);

        F16x8 As_, Ac_;
#pragma unroll
        for (int jj = 0; jj < 4; ++jj) {
            As_.p[jj] = __builtin_amdgcn_cvt_pkrtz(sv[2 * jj], sv[2 * jj + 1]);
            Ac_.p[jj] = __builtin_amdgcn_cvt_pkrtz(cv[2 * jj], cv[2 * jj + 1]);
        }

        f32x4 acc = {};
        acc = __builtin_amdgcn_mfma_f32_16x16x32_f16(As_.v, Bs_.v, acc, 0, 0, 0);
        acc = __builtin_amdgcn_mfma_f32_16x16x32_f16(Ac_.v, Bc_.v, acc, 0, 0, 0);

        // epilogue: key m = m0 + quad*4 + rr, head n; permuted pos in m.
        const int mrow = m0 + quad * 4;
        const int4 mk = *(const int4*)(mask + b * Nv + mrow);
        if (n < Hv) {
            const int* mkp = (const int*)&mk;
            unsigned short* dst = (unsigned short*)LB +
                                  ((size_t)(b * Hv + n) * Nv + q) * Nv;
            const int pos0 = quad * 64 + (w * 4 + i);
#pragma unroll
            for (int rr = 0; rr < 4; ++rr) {
                const float val = fmaxf(acc[rr] + bias_n, 1e-6f);
                const float lb = __logf(val) + (mkp[rr] ? 0.0f : -30000.0f);
                dst[pos0 + rr * 16] = __half_as_ushort(__float2half(lb));
            }
        }
    }
}

// ---------------------------------------------------------------------------
// attn3 (MFMA): block=(64q, h, b), 4 waves; wave owns 16 q rows.
// LB (permuted) preloaded as MFMA C accumulator; Q pre-scaled 1/8.
// Softmax in registers; P -> LDS (aliasing dead K); PV vs V^T.
// LDS: Qs 9.2K + Ks/Pb 36.9K + Vt 33.8K = 78K -> 2 blocks/CU.
// ---------------------------------------------------------------------------
__global__ __launch_bounds__(256) void attn3_kernel(
    const unsigned short* __restrict__ Qb2, const unsigned short* __restrict__ Kb2,
    const unsigned short* __restrict__ Vt2, const __half* __restrict__ LB,
    unsigned short* __restrict__ CTXb)
{
    const int qt = blockIdx.x, h = blockIdx.y, b = blockIdx.z;
    const int q0 = qt * 64;
    const int t = threadIdx.x, w = t >> 6, lane = t & 63;
    const int fr = lane & 15, fq = lane >> 4;

    __shared__ unsigned short Qs[64][72];
    __shared__ unsigned short Ks[256][72];
    __shared__ unsigned short Vt[64][264];
    unsigned short (*Pb)[264] = (unsigned short (*)[264])&Ks[0][0];

#pragma unroll
    for (int i = 0; i < 2; ++i) {          // Q
        const int idx = t + i * 256;
        const int row = idx >> 3, cu = idx & 7;
        *(bf16x8*)&Qs[row][cu * 8] =
            *(const bf16x8*)(Qb2 + (size_t)(b * Nv + q0 + row) * Dv + h * 64 + cu * 8);
    }
#pragma unroll
    for (int i = 0; i < 8; ++i) {          // K
        const int idx = t + i * 256;
        const int row = idx >> 3, cu = idx & 7;
        *(bf16x8*)&Ks[row][cu * 8] =
            *(const bf16x8*)(Kb2 + (size_t)(b * Nv + row) * Dv + h * 64 + cu * 8);
    }
#pragma unroll
    for (int i = 0; i < 8; ++i) {          // V^T
        const int idx = t + i * 256;
        const int row = idx >> 5, cu = idx & 31;
        *(bf16x8*)&Vt[row][cu * 8] =
            *(const bf16x8*)(Vt2 + (size_t)b * (Dv * Nv) + (h * 64 + row) * Nv + cu * 8);
    }

    // ---- acc init from permuted LB: row q=qb+r, 16 contiguous halfs @ fr*16
    f32x4 acc[16];
    const int qb = q0 + w * 16 + fq * 4;
    const __half* lbp = LB + ((size_t)(b * Hv + h) * Nv + qb) * Nv + fr * 16;
#pragma unroll
    for (int r = 0; r < 4; ++r) {
        union { int4 v; __half hs[8]; } u0, u1;
        const int4* p = (const int4*)(lbp + (size_t)r * Nv);
        u0.v = p[0]; u1.v = p[1];
#pragma unroll
        for (int nt = 0; nt < 8; ++nt) acc[nt][r]     = __half2float(u0.hs[nt]);
#pragma unroll
        for (int nt = 0; nt < 8; ++nt) acc[nt + 8][r] = __half2float(u1.hs[nt]);
    }

    __syncthreads();

    // ---- QK^T ----
    const bf16x8 aq0 = *(const bf16x8*)&Qs[w * 16 + fr][fq * 8];
    const bf16x8 aq1 = *(const bf16x8*)&Qs[w * 16 + fr][32 + fq * 8];
#pragma unroll
    for (int nt = 0; nt < 16; ++nt) {
        const bf16x8 bk0 = *(const bf16x8*)&Ks[nt * 16 + fr][fq * 8];
        const bf16x8 bk1 = *(const bf16x8*)&Ks[nt * 16 + fr][32 + fq * 8];
        acc[nt] = __builtin_amdgcn_mfma_f32_16x16x32_bf16(aq0, bk0, acc[nt], 0, 0, 0);
        acc[nt] = __builtin_amdgcn_mfma_f32_16x16x32_bf16(aq1, bk1, acc[nt], 0, 0, 0);
    }

    // ---- softmax in registers ----
    float ri[4];
#pragma unroll
    for (int r = 0; r < 4; ++r) {
        float mx = acc[0][r];
#pragma unroll
        for (int nt = 1; nt < 16; ++nt) mx = fmaxf(mx, acc[nt][r]);
        mx = fmaxf(mx, __shfl_xor(mx, 1));
        mx = fmaxf(mx, __shfl_xor(mx, 2));
        mx = fmaxf(mx, __shfl_xor(mx, 4));
        mx = fmaxf(mx, __shfl_xor(mx, 8));
        float s = 0.0f;
#pragma unroll
        for (int nt = 0; nt < 16; ++nt) {
            const float e = __expf(acc[nt][r] - mx);
            acc[nt][r] = e;
            s += e;
        }
        s += __shfl_xor(s, 1);
        s += __shfl_xor(s, 2);
        s += __shfl_xor(s, 4);
        s += __shfl_xor(s, 8);
        ri[r] = 1.0f / s;
    }

    __syncthreads();   // all Ks reads complete before P overwrites the buffer

#pragma unroll
    for (int nt = 0; nt < 16; ++nt)
#pragma unroll
        for (int r = 0; r < 4; ++r)
            Pb[w * 16 + fq * 4 + r][nt * 16 + fr] = f2bf(acc[nt][r] * ri[r]);

    // ---- PV ----
    f32x4 o[4] = {};
#pragma unroll
    for (int kt = 0; kt < 8; ++kt) {
        const bf16x8 ap = *(const bf16x8*)&Pb[w * 16 + fr][kt * 32 + fq * 8];
#pragma unroll
        for (int nt2 = 0; nt2 < 4; ++nt2) {
            const bf16x8 bv_ = *(const bf16x8*)&Vt[nt2 * 16 + fr][kt * 32 + fq * 8];
            o[nt2] = __builtin_amdgcn_mfma_f32_16x16x32_bf16(ap, bv_, o[nt2], 0, 0, 0);
        }
    }

#pragma unroll
    for (int nt2 = 0; nt2 < 4; ++nt2)
#pragma unroll
        for (int r = 0; r < 4; ++r)
            CTXb[(size_t)(b * Nv + qb + r) * Dv + h * 64 + nt2 * 16 + fr] =
                f2bf(o[nt2][r]);
}

// ---------------------------------------------------------------------------
extern "C" void kernel_launch(void* const* d_in, const int* in_sizes, int n_in,
                              void* d_out, int out_size, void* d_ws, size_t ws_size,
                              hipStream_t stream) {
    (void)in_sizes; (void)n_in; (void)out_size; (void)ws_size;

    const float* inq  = (const float*)d_in[0];
    const float* ink  = (const float*)d_in[1];
    const float* inv  = (const float*)d_in[2];
    const float* box  = (const float*)d_in[3];
    const int*   mask = (const int*)d_in[4];
    const float* Wq   = (const float*)d_in[5];
    const float* bq   = (const float*)d_in[6];
    const float* Wk   = (const float*)d_in[7];
    const float* bk   = (const float*)d_in[8];
    const float* Wv   = (const float*)d_in[9];
    const float* bv   = (const float*)d_in[10];
    const float* Wo   = (const float*)d_in[11];
    const float* bo   = (const float*)d_in[12];
    const float* WGw  = (const float*)d_in[13];
    const float* WGb  = (const float*)d_in[14];

    char* W = (char*)d_ws;
    const size_t MB = 1048576;
    unsigned short* Qb2  = (unsigned short*)(W + 0);        // 4 MB bf16 [b][m][512], pre-scaled 1/8
    unsigned short* Kb2  = (unsigned short*)(W + 4 * MB);   // 4 MB bf16 [b][m][512]
    unsigned short* Vt2  = (unsigned short*)(W + 8 * MB);   // 4 MB bf16 [b][d][m]
    unsigned short* Wt   = (unsigned short*)(W + 12 * MB);  // 2 MB (4 transposed weights)
    float*          bst  = (float*)(W + 14 * MB);           // 8 KB bias stack
    unsigned short* CTXb = (unsigned short*)(W + 15 * MB);  // 4 MB
    unsigned short* Ab   = (unsigned short*)(W + 20 * MB);  // 12 MB (3 bf16 input planes)
    __half*         LB   = (__half*)(W + 20 * MB);          // 16.8 MB, aliases Ab (dead after QKV)

    float* out = (float*)d_out;

    conv_b16_kernel<<<dim3(2048, 1, 3), 256, 0, stream>>>(inq, ink, inv, Ab);
    conv_w_kernel<<<dim3(8, 8, 4), 256, 0, stream>>>(Wq, Wk, Wv, Wo, bq, bk, bv, bo, Wt, bst);

    qkv_gemm_kernel<<<dim3(4, 32, 3), 256, 0, stream>>>(Ab, Wt, bst, Qb2, Kb2, Vt2);

    geo_mfma_kernel<<<dim3(Nv, Bv), 256, 0, stream>>>(box, mask, WGw, WGb, LB);

    attn3_kernel<<<dim3(4, 8, 16), 256, 0, stream>>>(Qb2, Kb2, Vt2, LB, CTXb);

    out_gemm_kernel<<<dim3(8, 32), 256, 0, stream>>>(CTXb, Wt + 3 * (Dv * Dv), bst + 3 * Dv, out);
}

// Round 9
// 169.027 us; speedup vs baseline: 1.1256x; 1.1226x over previous
//
#include <hip/hip_runtime.h>
#include <hip/hip_fp16.h>
#include <math.h>

#define Bv   16
#define Nv   256
#define Dv   512
#define Hv   8
#define MNv  4096          // B*N tokens

typedef __attribute__((ext_vector_type(8))) short bf16x8;
typedef __attribute__((ext_vector_type(4))) float f32x4;
typedef __fp16 fp16x8 __attribute__((ext_vector_type(8)));
typedef __fp16 fp16x2 __attribute__((ext_vector_type(2)));

__device__ __forceinline__ unsigned short f2bf(float f) {   // RNE
    unsigned u = __float_as_uint(f);
    u = u + 0x7FFFu + ((u >> 16) & 1u);
    return (unsigned short)(u >> 16);
}
__device__ __forceinline__ void gload_lds16(const void* g, void* l) {
    __builtin_amdgcn_global_load_lds(
        (const __attribute__((address_space(1))) unsigned int*)g,
        (__attribute__((address_space(3))) unsigned int*)l, 16, 0, 0);
}

// HW sin/cos: v_sin_f32/v_cos_f32 take REVOLUTIONS (D=sin(S0*2pi)).
__device__ __forceinline__ void fast_sincos(float x, float* s, float* c) {
    const float rev = x * 0.15915494309189535f;   // 1/(2*pi)
    const float fr  = rev - floorf(rev);
    *s = __builtin_amdgcn_sinf(fr);
    *c = __builtin_amdgcn_cosf(fr);
}

// ---------------------------------------------------------------------------
// fp32 -> bf16 for the 3 projection inputs (z selects).
// ---------------------------------------------------------------------------
__global__ __launch_bounds__(256) void conv_b16_kernel(
    const float* __restrict__ xq, const float* __restrict__ xk,
    const float* __restrict__ xv, unsigned short* __restrict__ Ab)
{
    const int z = blockIdx.z;
    const float* src = (z == 0) ? xq : (z == 1) ? xk : xv;
    const size_t base = (size_t)z * (MNv * Dv);
    const int idx = (blockIdx.x * 256 + threadIdx.x) * 4;
    float4 x = *(const float4*)(src + idx);
    ushort4 h;
    h.x = f2bf(x.x); h.y = f2bf(x.y); h.z = f2bf(x.z); h.w = f2bf(x.w);
    *(ushort4*)(Ab + base + idx) = h;
}

// ---------------------------------------------------------------------------
// W[k][n] fp32 -> Wt[n][k] bf16 (transposed), all 4 weights (z); also stacks
// the 4 biases into biasStack[z][512].
// ---------------------------------------------------------------------------
__global__ __launch_bounds__(256) void conv_w_kernel(
    const float* __restrict__ Wq, const float* __restrict__ Wk,
    const float* __restrict__ Wv, const float* __restrict__ Wo,
    const float* __restrict__ bq, const float* __restrict__ bk,
    const float* __restrict__ bv, const float* __restrict__ bo,
    unsigned short* __restrict__ Wt, float* __restrict__ biasStack)
{
    const int z = blockIdx.z;
    const float* W = (z == 0) ? Wq : (z == 1) ? Wk : (z == 2) ? Wv : Wo;
    const float* b = (z == 0) ? bq : (z == 1) ? bk : (z == 2) ? bv : bo;
    const int n0 = blockIdx.x * 64, k0 = blockIdx.y * 64;
    const int t = threadIdx.x;
    __shared__ float T[64][65];
    const int col = t & 63, rb = t >> 6;
#pragma unroll
    for (int i = 0; i < 16; ++i) {
        const int row = i * 4 + rb;
        T[row][col] = W[(k0 + row) * Dv + n0 + col];
    }
    __syncthreads();
#pragma unroll
    for (int i = 0; i < 16; ++i) {
        const int row = i * 4 + rb;
        Wt[z * (Dv * Dv) + (n0 + row) * Dv + k0 + col] = f2bf(T[col][row]);
    }
    if (blockIdx.x == 0 && blockIdx.y == 0) {
        biasStack[z * Dv + t]       = b[t];
        biasStack[z * Dv + t + 256] = b[t + 256];
    }
}

// ---------------------------------------------------------------------------
// Fused Q/K/V projection GEMM, one launch, grid (4,32,3) = 384 blocks.
// z=0: Q bf16 row-major scaled 1/8; z=1: K bf16 row-major;
// z=2: V bf16 transposed per-batch [b][d][m].
// ---------------------------------------------------------------------------
__global__ __launch_bounds__(256) void qkv_gemm_kernel(
    const unsigned short* __restrict__ Ab, const unsigned short* __restrict__ Wt,
    const float* __restrict__ bst, unsigned short* __restrict__ Qb2,
    unsigned short* __restrict__ Kb2, unsigned short* __restrict__ Vt2)
{
    const int z = blockIdx.z;
    const unsigned short* A = Ab + (size_t)z * (MNv * Dv);
    const unsigned short* Wz = Wt + (size_t)z * (Dv * Dv);
    const float* bias = bst + z * Dv;

    const int n0 = blockIdx.x * 128;
    const int m0 = blockIdx.y * 128;
    const int t = threadIdx.x;
    const int w = t >> 6, lane = t & 63;
    const int wm = w & 1, wn = w >> 1;

    __shared__ unsigned short As[128][32];
    __shared__ unsigned short Bs[128][32];

    f32x4 acc[4][4] = {};

    const int sr = lane >> 2;
    const int sk = (lane & 3) * 8;
    const int fr = lane & 15;
    const int fk = (lane >> 4) * 8;

    for (int k0 = 0; k0 < Dv; k0 += 32) {
        __syncthreads();
#pragma unroll
        for (int j = 0; j < 2; ++j) {
            const int row = w * 32 + j * 16 + sr;
            gload_lds16(A  + (size_t)(m0 + row) * Dv + k0 + sk, &As[w * 32 + j * 16][0]);
            gload_lds16(Wz + (size_t)(n0 + row) * Dv + k0 + sk, &Bs[w * 32 + j * 16][0]);
        }
        __syncthreads();

        bf16x8 af[4], bfr[4];
#pragma unroll
        for (int mt = 0; mt < 4; ++mt)
            af[mt] = *(const bf16x8*)&As[wm * 64 + mt * 16 + fr][fk];
#pragma unroll
        for (int nt = 0; nt < 4; ++nt)
            bfr[nt] = *(const bf16x8*)&Bs[wn * 64 + nt * 16 + fr][fk];
#pragma unroll
        for (int mt = 0; mt < 4; ++mt)
#pragma unroll
            for (int nt = 0; nt < 4; ++nt)
                acc[mt][nt] = __builtin_amdgcn_mfma_f32_16x16x32_bf16(
                    af[mt], bfr[nt], acc[mt][nt], 0, 0, 0);
    }

    const int er = (lane >> 4) * 4;
    const int ec = lane & 15;
    const float scale = (z == 0) ? 0.125f : 1.0f;
#pragma unroll
    for (int nt = 0; nt < 4; ++nt) {
        const int gn = n0 + wn * 64 + nt * 16 + ec;
        const float bv_ = bias[gn];
#pragma unroll
        for (int mt = 0; mt < 4; ++mt) {
            const int gm = m0 + wm * 64 + mt * 16 + er;
            if (z == 2) {
                ushort4 o;
                o.x = f2bf(acc[mt][nt][0] + bv_);
                o.y = f2bf(acc[mt][nt][1] + bv_);
                o.z = f2bf(acc[mt][nt][2] + bv_);
                o.w = f2bf(acc[mt][nt][3] + bv_);
                *(ushort4*)(Vt2 + ((size_t)(gm >> 8) * Dv + gn) * Nv + (gm & 255)) = o;
            } else {
                unsigned short* cp = ((z == 0) ? Qb2 : Kb2) + (size_t)gm * Dv + gn;
#pragma unroll
                for (int r = 0; r < 4; ++r)
                    cp[(size_t)r * Dv] = f2bf((acc[mt][nt][r] + bv_) * scale);
            }
        }
    }
}

// ---------------------------------------------------------------------------
// Output GEMM: out[4096][512] = CTXb @ Wo^T + bias, fp32.  128x64 tile,
// grid (8,32) = 256 blocks (full GPU).
// ---------------------------------------------------------------------------
__global__ __launch_bounds__(256) void out_gemm_kernel(
    const unsigned short* __restrict__ A, const unsigned short* __restrict__ Wz,
    const float* __restrict__ bias, float* __restrict__ C)
{
    const int n0 = blockIdx.x * 64;
    const int m0 = blockIdx.y * 128;
    const int t = threadIdx.x;
    const int w = t >> 6, lane = t & 63;
    const int wm = w & 1, wn = w >> 1;

    __shared__ unsigned short As[128][32];
    __shared__ unsigned short Bs[64][32];

    f32x4 acc[4][2] = {};

    const int sr = lane >> 2;
    const int sk = (lane & 3) * 8;
    const int fr = lane & 15;
    const int fk = (lane >> 4) * 8;

    for (int k0 = 0; k0 < Dv; k0 += 32) {
        __syncthreads();
#pragma unroll
        for (int j = 0; j < 2; ++j) {
            const int row = w * 32 + j * 16 + sr;
            gload_lds16(A + (size_t)(m0 + row) * Dv + k0 + sk, &As[w * 32 + j * 16][0]);
        }
        gload_lds16(Wz + (size_t)(n0 + w * 16 + sr) * Dv + k0 + sk, &Bs[w * 16][0]);
        __syncthreads();

        bf16x8 af[4], bfr[2];
#pragma unroll
        for (int mt = 0; mt < 4; ++mt)
            af[mt] = *(const bf16x8*)&As[wm * 64 + mt * 16 + fr][fk];
#pragma unroll
        for (int nt = 0; nt < 2; ++nt)
            bfr[nt] = *(const bf16x8*)&Bs[wn * 32 + nt * 16 + fr][fk];
#pragma unroll
        for (int mt = 0; mt < 4; ++mt)
#pragma unroll
            for (int nt = 0; nt < 2; ++nt)
                acc[mt][nt] = __builtin_amdgcn_mfma_f32_16x16x32_bf16(
                    af[mt], bfr[nt], acc[mt][nt], 0, 0, 0);
    }

    const int er = (lane >> 4) * 4;
    const int ec = lane & 15;
#pragma unroll
    for (int nt = 0; nt < 2; ++nt) {
        const int gn = n0 + wn * 32 + nt * 16 + ec;
        const float bv_ = bias[gn];
#pragma unroll
        for (int mt = 0; mt < 4; ++mt) {
            const int gm = m0 + wm * 64 + mt * 16 + er;
            float* cp = C + (size_t)gm * Dv + gn;
#pragma unroll
            for (int r = 0; r < 4; ++r)
                cp[(size_t)r * Dv] = acc[mt][nt][r] + bv_;
        }
    }
}

// ---------------------------------------------------------------------------
// Geometric log-bias via MFMA, v6: LDS-staged coalesced output.
// Evidence (R6/R7/R8): duration pinned at 50.6us across 4x VALU changes ->
// bound by the scattered per-lane 2B global stores (32 cache lines per store
// instr).  Fix: write the block's 8x256-half tile into LDS (padded rows),
// then one coalesced pass: thread t -> head t>>5, 16B chunk t&31.
// Block=(q,b), 256 thr = 4 waves.  LB permuted in m:
// LB[b][h][q][(m&15)*16 + (m>>4)] for attn3's contiguous C-frag init.
// ---------------------------------------------------------------------------
__global__ __launch_bounds__(256) void geo_mfma_kernel(
    const float* __restrict__ box, const int* __restrict__ mask,
    const float* __restrict__ WGw, const float* __restrict__ WGb,
    __half* __restrict__ LB)
{
    const int q = blockIdx.x;
    const int b = blockIdx.y;
    const int t = threadIdx.x;
    const int w = t >> 6, lane = t & 63;
    const int n = lane & 15;
    const int quad = lane >> 4;

    __shared__ unsigned short Lst[Hv][264];   // 264-half rows: 4-way max bank aliasing

    const float4 bq_ = *(const float4*)(box + (b * Nv + q) * 4);
    const float cxq = (bq_.x + bq_.z) * 0.5f;
    const float cyq = (bq_.y + bq_.w) * 0.5f;
    const float wq  = bq_.z - bq_.x + 1.0f;
    const float hq  = bq_.w - bq_.y + 1.0f;

    union F16x8 { fp16x8 v; fp16x2 p[4]; };
    F16x8 Bs_, Bc_;
    Bs_.v = (fp16x8){}; Bc_.v = (fp16x8){};
    float bias_n = 0.0f;
    if (n < Hv) {
        bias_n = WGb[n];
#pragma unroll
        for (int jj = 0; jj < 4; ++jj) {
            Bs_.p[jj] = __builtin_amdgcn_cvt_pkrtz(WGw[n * 64 + quad * 8 + 2 * jj],
                                                   WGw[n * 64 + quad * 8 + 2 * jj + 1]);
            Bc_.p[jj] = __builtin_amdgcn_cvt_pkrtz(WGw[n * 64 + 32 + quad * 8 + 2 * jj],
                                                   WGw[n * 64 + 32 + quad * 8 + 2 * jj + 1]);
        }
    }

    const float dimm[8] = {1.0f, 0.42169650342f, 0.17782794100f, 0.07498942093f,
                           0.03162277660f, 0.01333521432f, 0.00562341325f, 0.00237137371f};
    const bool isCtr = (quad < 2);
    const bool isY   = (quad & 1);
    const float cq  = isY ? cyq : cxq;
    const float sq_ = isY ? hq : wq;

#pragma unroll
    for (int i = 0; i < 4; ++i) {
        const int m0 = (w * 4 + i) * 16;
        const float4 bm = *(const float4*)(box + (b * Nv + m0 + n) * 4);
        const float cxm = (bm.x + bm.z) * 0.5f;
        const float cym = (bm.y + bm.w) * 0.5f;
        const float wm  = bm.z - bm.x + 1.0f;
        const float hm  = bm.w - bm.y + 1.0f;
        const float cm_ = isY ? cym : cxm;
        const float sm_ = isY ? hm : wm;
        const float top = isCtr ? fabsf(cq - cm_) : sq_;
        const float bot = isCtr ? sq_ : sm_;
        float r = top / bot;
        if (isCtr) r = fmaxf(r, 1e-3f);
        const float base = 100.0f * __logf(r);

        float sv[8], cv[8];
#pragma unroll
        for (int j = 0; j < 8; ++j)
            fast_sincos(base * dimm[j], &sv[j], &cv[j]);

        F16x8 As_, Ac_;
#pragma unroll
        for (int jj = 0; jj < 4; ++jj) {
            As_.p[jj] = __builtin_amdgcn_cvt_pkrtz(sv[2 * jj], sv[2 * jj + 1]);
            Ac_.p[jj] = __builtin_amdgcn_cvt_pkrtz(cv[2 * jj], cv[2 * jj + 1]);
        }

        f32x4 acc = {};
        acc = __builtin_amdgcn_mfma_f32_16x16x32_f16(As_.v, Bs_.v, acc, 0, 0, 0);
        acc = __builtin_amdgcn_mfma_f32_16x16x32_f16(Ac_.v, Bc_.v, acc, 0, 0, 0);

        // epilogue -> LDS: key m = m0 + quad*4 + rr, head n.
        // pos(m) = (m&15)*16 + (m>>4) = (quad*4+rr)*16 + (w*4+i)
        const int mrow = m0 + quad * 4;
        const int4 mk = *(const int4*)(mask + b * Nv + mrow);
        if (n < Hv) {
            const int* mkp = (const int*)&mk;
            const int pos0 = quad * 64 + (w * 4 + i);
#pragma unroll
            for (int rr = 0; rr < 4; ++rr) {
                const float val = fmaxf(acc[rr] + bias_n, 1e-6f);
                const float lb = __logf(val) + (mkp[rr] ? 0.0f : -30000.0f);
                Lst[n][pos0 + rr * 16] = __half_as_ushort(__float2half(lb));
            }
        }
    }

    __syncthreads();

    // coalesced write-out: 32 threads per head-row, 16B each (512B contiguous)
    const int h = t >> 5, c = t & 31;
    unsigned short* dst = (unsigned short*)LB +
                          ((size_t)(b * Hv + h) * Nv + q) * Nv + c * 8;
    *(int4*)dst = *(const int4*)&Lst[h][c * 8];
}

// ---------------------------------------------------------------------------
// attn3 (MFMA): block=(64q, h, b), 4 waves; wave owns 16 q rows.
// LB (permuted) preloaded as MFMA C accumulator; Q pre-scaled 1/8.
// Softmax in registers; P -> LDS (aliasing dead K); PV vs V^T.
// LDS: Qs 9.2K + Ks/Pb 36.9K + Vt 33.8K = 78K -> 2 blocks/CU.
// ---------------------------------------------------------------------------
__global__ __launch_bounds__(256) void attn3_kernel(
    const unsigned short* __restrict__ Qb2, const unsigned short* __restrict__ Kb2,
    const unsigned short* __restrict__ Vt2, const __half* __restrict__ LB,
    unsigned short* __restrict__ CTXb)
{
    const int qt = blockIdx.x, h = blockIdx.y, b = blockIdx.z;
    const int q0 = qt * 64;
    const int t = threadIdx.x, w = t >> 6, lane = t & 63;
    const int fr = lane & 15, fq = lane >> 4;

    __shared__ unsigned short Qs[64][72];
    __shared__ unsigned short Ks[256][72];
    __shared__ unsigned short Vt[64][264];
    unsigned short (*Pb)[264] = (unsigned short (*)[264])&Ks[0][0];

#pragma unroll
    for (int i = 0; i < 2; ++i) {          // Q
        const int idx = t + i * 256;
        const int row = idx >> 3, cu = idx & 7;
        *(bf16x8*)&Qs[row][cu * 8] =
            *(const bf16x8*)(Qb2 + (size_t)(b * Nv + q0 + row) * Dv + h * 64 + cu * 8);
    }
#pragma unroll
    for (int i = 0; i < 8; ++i) {          // K
        const int idx = t + i * 256;
        const int row = idx >> 3, cu = idx & 7;
        *(bf16x8*)&Ks[row][cu * 8] =
            *(const bf16x8*)(Kb2 + (size_t)(b * Nv + row) * Dv + h * 64 + cu * 8);
    }
#pragma unroll
    for (int i = 0; i < 8; ++i) {          // V^T
        const int idx = t + i * 256;
        const int row = idx >> 5, cu = idx & 31;
        *(bf16x8*)&Vt[row][cu * 8] =
            *(const bf16x8*)(Vt2 + (size_t)b * (Dv * Nv) + (h * 64 + row) * Nv + cu * 8);
    }

    // ---- acc init from permuted LB: row q=qb+r, 16 contiguous halfs @ fr*16
    f32x4 acc[16];
    const int qb = q0 + w * 16 + fq * 4;
    const __half* lbp = LB + ((size_t)(b * Hv + h) * Nv + qb) * Nv + fr * 16;
#pragma unroll
    for (int r = 0; r < 4; ++r) {
        union { int4 v; __half hs[8]; } u0, u1;
        const int4* p = (const int4*)(lbp + (size_t)r * Nv);
        u0.v = p[0]; u1.v = p[1];
#pragma unroll
        for (int nt = 0; nt < 8; ++nt) acc[nt][r]     = __half2float(u0.hs[nt]);
#pragma unroll
        for (int nt = 0; nt < 8; ++nt) acc[nt + 8][r] = __half2float(u1.hs[nt]);
    }

    __syncthreads();

    // ---- QK^T ----
    const bf16x8 aq0 = *(const bf16x8*)&Qs[w * 16 + fr][fq * 8];
    const bf16x8 aq1 = *(const bf16x8*)&Qs[w * 16 + fr][32 + fq * 8];
#pragma unroll
    for (int nt = 0; nt < 16; ++nt) {
        const bf16x8 bk0 = *(const bf16x8*)&Ks[nt * 16 + fr][fq * 8];
        const bf16x8 bk1 = *(const bf16x8*)&Ks[nt * 16 + fr][32 + fq * 8];
        acc[nt] = __builtin_amdgcn_mfma_f32_16x16x32_bf16(aq0, bk0, acc[nt], 0, 0, 0);
        acc[nt] = __builtin_amdgcn_mfma_f32_16x16x32_bf16(aq1, bk1, acc[nt], 0, 0, 0);
    }

    // ---- softmax in registers ----
    float ri[4];
#pragma unroll
    for (int r = 0; r < 4; ++r) {
        float mx = acc[0][r];
#pragma unroll
        for (int nt = 1; nt < 16; ++nt) mx = fmaxf(mx, acc[nt][r]);
        mx = fmaxf(mx, __shfl_xor(mx, 1));
        mx = fmaxf(mx, __shfl_xor(mx, 2));
        mx = fmaxf(mx, __shfl_xor(mx, 4));
        mx = fmaxf(mx, __shfl_xor(mx, 8));
        float s = 0.0f;
#pragma unroll
        for (int nt = 0; nt < 16; ++nt) {
            const float e = __expf(acc[nt][r] - mx);
            acc[nt][r] = e;
            s += e;
        }
        s += __shfl_xor(s, 1);
        s += __shfl_xor(s, 2);
        s += __shfl_xor(s, 4);
        s += __shfl_xor(s, 8);
        ri[r] = 1.0f / s;
    }

    __syncthreads();   // all Ks reads complete before P overwrites the buffer

#pragma unroll
    for (int nt = 0; nt < 16; ++nt)
#pragma unroll
        for (int r = 0; r < 4; ++r)
            Pb[w * 16 + fq * 4 + r][nt * 16 + fr] = f2bf(acc[nt][r] * ri[r]);

    // ---- PV ----
    f32x4 o[4] = {};
#pragma unroll
    for (int kt = 0; kt < 8; ++kt) {
        const bf16x8 ap = *(const bf16x8*)&Pb[w * 16 + fr][kt * 32 + fq * 8];
#pragma unroll
        for (int nt2 = 0; nt2 < 4; ++nt2) {
            const bf16x8 bv_ = *(const bf16x8*)&Vt[nt2 * 16 + fr][kt * 32 + fq * 8];
            o[nt2] = __builtin_amdgcn_mfma_f32_16x16x32_bf16(ap, bv_, o[nt2], 0, 0, 0);
        }
    }

#pragma unroll
    for (int nt2 = 0; nt2 < 4; ++nt2)
#pragma unroll
        for (int r = 0; r < 4; ++r)
            CTXb[(size_t)(b * Nv + qb + r) * Dv + h * 64 + nt2 * 16 + fr] =
                f2bf(o[nt2][r]);
}

// ---------------------------------------------------------------------------
extern "C" void kernel_launch(void* const* d_in, const int* in_sizes, int n_in,
                              void* d_out, int out_size, void* d_ws, size_t ws_size,
                              hipStream_t stream) {
    (void)in_sizes; (void)n_in; (void)out_size; (void)ws_size;

    const float* inq  = (const float*)d_in[0];
    const float* ink  = (const float*)d_in[1];
    const float* inv  = (const float*)d_in[2];
    const float* box  = (const float*)d_in[3];
    const int*   mask = (const int*)d_in[4];
    const float* Wq   = (const float*)d_in[5];
    const float* bq   = (const float*)d_in[6];
    const float* Wk   = (const float*)d_in[7];
    const float* bk   = (const float*)d_in[8];
    const float* Wv   = (const float*)d_in[9];
    const float* bv   = (const float*)d_in[10];
    const float* Wo   = (const float*)d_in[11];
    const float* bo   = (const float*)d_in[12];
    const float* WGw  = (const float*)d_in[13];
    const float* WGb  = (const float*)d_in[14];

    char* W = (char*)d_ws;
    const size_t MB = 1048576;
    unsigned short* Qb2  = (unsigned short*)(W + 0);        // 4 MB bf16 [b][m][512], pre-scaled 1/8
    unsigned short* Kb2  = (unsigned short*)(W + 4 * MB);   // 4 MB bf16 [b][m][512]
    unsigned short* Vt2  = (unsigned short*)(W + 8 * MB);   // 4 MB bf16 [b][d][m]
    unsigned short* Wt   = (unsigned short*)(W + 12 * MB);  // 2 MB (4 transposed weights)
    float*          bst  = (float*)(W + 14 * MB);           // 8 KB bias stack
    unsigned short* CTXb = (unsigned short*)(W + 15 * MB);  // 4 MB
    unsigned short* Ab   = (unsigned short*)(W + 20 * MB);  // 12 MB (3 bf16 input planes)
    __half*         LB   = (__half*)(W + 20 * MB);          // 16.8 MB, aliases Ab (dead after QKV)

    float* out = (float*)d_out;

    conv_b16_kernel<<<dim3(2048, 1, 3), 256, 0, stream>>>(inq, ink, inv, Ab);
    conv_w_kernel<<<dim3(8, 8, 4), 256, 0, stream>>>(Wq, Wk, Wv, Wo, bq, bk, bv, bo, Wt, bst);

    qkv_gemm_kernel<<<dim3(4, 32, 3), 256, 0, stream>>>(Ab, Wt, bst, Qb2, Kb2, Vt2);

    geo_mfma_kernel<<<dim3(Nv, Bv), 256, 0, stream>>>(box, mask, WGw, WGb, LB);

    attn3_kernel<<<dim3(4, 8, 16), 256, 0, stream>>>(Qb2, Kb2, Vt2, LB, CTXb);

    out_gemm_kernel<<<dim3(8, 32), 256, 0, stream>>>(CTXb, Wt + 3 * (Dv * Dv), bst + 3 * Dv, out);
}

// Round 10
// 161.098 us; speedup vs baseline: 1.1810x; 1.0492x over previous
//
#include <hip/hip_runtime.h>
#include <hip/hip_fp16.h>
#include <math.h>

#define Bv   16
#define Nv   256
#define Dv   512
#define Hv   8
#define MNv  4096          // B*N tokens

typedef __attribute__((ext_vector_type(8))) short bf16x8;
typedef __attribute__((ext_vector_type(4))) float f32x4;
typedef __fp16 fp16x8 __attribute__((ext_vector_type(8)));
typedef __fp16 fp16x2 __attribute__((ext_vector_type(2)));

__device__ __forceinline__ unsigned short f2bf(float f) {   // RNE
    unsigned u = __float_as_uint(f);
    u = u + 0x7FFFu + ((u >> 16) & 1u);
    return (unsigned short)(u >> 16);
}
__device__ __forceinline__ void gload_lds16(const void* g, void* l) {
    __builtin_amdgcn_global_load_lds(
        (const __attribute__((address_space(1))) unsigned int*)g,
        (__attribute__((address_space(3))) unsigned int*)l, 16, 0, 0);
}

// HW sin/cos: v_sin_f32/v_cos_f32 take REVOLUTIONS (D=sin(S0*2pi)).
__device__ __forceinline__ void fast_sincos(float x, float* s, float* c) {
    const float rev = x * 0.15915494309189535f;   // 1/(2*pi)
    const float fr  = rev - floorf(rev);
    *s = __builtin_amdgcn_sinf(fr);
    *c = __builtin_amdgcn_cosf(fr);
}

// ---------------------------------------------------------------------------
// MEGA-1: geo-bias (blocks 0..4095) + fp32->bf16 input conv (4096..10239)
// + weight transpose conv (10240..10495), one launch.  geo is trans-bound,
// conv is HBM-bound -> co-resident waves overlap on different pipes (m114).
// geo blocks dispatched first (long pole).
// ---------------------------------------------------------------------------
__global__ __launch_bounds__(256) void mega1_kernel(
    const float* __restrict__ box, const int* __restrict__ mask,
    const float* __restrict__ WGw, const float* __restrict__ WGb,
    __half* __restrict__ LB,
    const float* __restrict__ xq, const float* __restrict__ xk,
    const float* __restrict__ xv, unsigned short* __restrict__ Ab,
    const float* __restrict__ Wq, const float* __restrict__ Wk,
    const float* __restrict__ Wv, const float* __restrict__ Wo,
    const float* __restrict__ bq, const float* __restrict__ bk,
    const float* __restrict__ bv, const float* __restrict__ bo,
    unsigned short* __restrict__ Wt, float* __restrict__ biasStack)
{
    __shared__ __align__(16) char smraw[64 * 65 * 4];   // union: geo Lst / conv_w T
    const int bid = blockIdx.x;
    const int t = threadIdx.x;

    if (bid < 4096) {
        // ================= geo-bias =================
        unsigned short (*Lst)[264] = (unsigned short (*)[264])smraw;
        const int q = bid & 255;
        const int b = bid >> 8;
        const int w = t >> 6, lane = t & 63;
        const int n = lane & 15;
        const int quad = lane >> 4;

        const float4 bq_ = *(const float4*)(box + (b * Nv + q) * 4);
        const float cxq = (bq_.x + bq_.z) * 0.5f;
        const float cyq = (bq_.y + bq_.w) * 0.5f;
        const float wq  = bq_.z - bq_.x + 1.0f;
        const float hq  = bq_.w - bq_.y + 1.0f;

        union F16x8 { fp16x8 v; fp16x2 p[4]; };
        F16x8 Bs_, Bc_;
        Bs_.v = (fp16x8){}; Bc_.v = (fp16x8){};
        float bias_n = 0.0f;
        if (n < Hv) {
            bias_n = WGb[n];
#pragma unroll
            for (int jj = 0; jj < 4; ++jj) {
                Bs_.p[jj] = __builtin_amdgcn_cvt_pkrtz(WGw[n * 64 + quad * 8 + 2 * jj],
                                                       WGw[n * 64 + quad * 8 + 2 * jj + 1]);
                Bc_.p[jj] = __builtin_amdgcn_cvt_pkrtz(WGw[n * 64 + 32 + quad * 8 + 2 * jj],
                                                       WGw[n * 64 + 32 + quad * 8 + 2 * jj + 1]);
            }
        }

        const float dimm[8] = {1.0f, 0.42169650342f, 0.17782794100f, 0.07498942093f,
                               0.03162277660f, 0.01333521432f, 0.00562341325f, 0.00237137371f};
        const bool isCtr = (quad < 2);
        const bool isY   = (quad & 1);
        const float cq  = isY ? cyq : cxq;
        const float sq_ = isY ? hq : wq;

#pragma unroll
        for (int i = 0; i < 4; ++i) {
            const int m0 = (w * 4 + i) * 16;
            const float4 bm = *(const float4*)(box + (b * Nv + m0 + n) * 4);
            const float cxm = (bm.x + bm.z) * 0.5f;
            const float cym = (bm.y + bm.w) * 0.5f;
            const float wm  = bm.z - bm.x + 1.0f;
            const float hm  = bm.w - bm.y + 1.0f;
            const float cm_ = isY ? cym : cxm;
            const float sm_ = isY ? hm : wm;
            const float top = isCtr ? fabsf(cq - cm_) : sq_;
            const float bot = isCtr ? sq_ : sm_;
            float r = top / bot;
            if (isCtr) r = fmaxf(r, 1e-3f);
            const float base = 100.0f * __logf(r);

            float sv[8], cv[8];
#pragma unroll
            for (int j = 0; j < 8; ++j)
                fast_sincos(base * dimm[j], &sv[j], &cv[j]);

            F16x8 As_, Ac_;
#pragma unroll
            for (int jj = 0; jj < 4; ++jj) {
                As_.p[jj] = __builtin_amdgcn_cvt_pkrtz(sv[2 * jj], sv[2 * jj + 1]);
                Ac_.p[jj] = __builtin_amdgcn_cvt_pkrtz(cv[2 * jj], cv[2 * jj + 1]);
            }

            f32x4 acc = {};
            acc = __builtin_amdgcn_mfma_f32_16x16x32_f16(As_.v, Bs_.v, acc, 0, 0, 0);
            acc = __builtin_amdgcn_mfma_f32_16x16x32_f16(Ac_.v, Bc_.v, acc, 0, 0, 0);

            const int mrow = m0 + quad * 4;
            const int4 mk = *(const int4*)(mask + b * Nv + mrow);
            if (n < Hv) {
                const int* mkp = (const int*)&mk;
                const int pos0 = quad * 64 + (w * 4 + i);
#pragma unroll
                for (int rr = 0; rr < 4; ++rr) {
                    const float val = fmaxf(acc[rr] + bias_n, 1e-6f);
                    const float lb = __logf(val) + (mkp[rr] ? 0.0f : -30000.0f);
                    Lst[n][pos0 + rr * 16] = __half_as_ushort(__float2half(lb));
                }
            }
        }

        __syncthreads();
        const int h = t >> 5, c = t & 31;
        unsigned short* dst = (unsigned short*)LB +
                              ((size_t)(b * Hv + h) * Nv + q) * Nv + c * 8;
        *(int4*)dst = *(const int4*)&Lst[h][c * 8];

    } else if (bid < 10240) {
        // ================= input fp32 -> bf16 =================
        const int i = bid - 4096;
        const int z = i >> 11;            // 0..2
        const int xblk = i & 2047;
        const float* src = (z == 0) ? xq : (z == 1) ? xk : xv;
        const size_t base = (size_t)z * (MNv * Dv);
        const int idx = (xblk * 256 + t) * 4;
        float4 x = *(const float4*)(src + idx);
        ushort4 h4;
        h4.x = f2bf(x.x); h4.y = f2bf(x.y); h4.z = f2bf(x.z); h4.w = f2bf(x.w);
        *(ushort4*)(Ab + base + idx) = h4;

    } else {
        // ================= weight transpose (fp32 W[k][n] -> bf16 Wt[n][k]) =====
        float (*T)[65] = (float (*)[65])smraw;
        const int i = bid - 10240;        // 0..255
        const int z = i >> 6;
        const int rem = i & 63;
        const int n0 = (rem & 7) * 64, k0 = (rem >> 3) * 64;
        const float* W = (z == 0) ? Wq : (z == 1) ? Wk : (z == 2) ? Wv : Wo;
        const float* b = (z == 0) ? bq : (z == 1) ? bk : (z == 2) ? bv : bo;
        const int col = t & 63, rb = t >> 6;
#pragma unroll
        for (int j = 0; j < 16; ++j) {
            const int row = j * 4 + rb;
            T[row][col] = W[(k0 + row) * Dv + n0 + col];
        }
        __syncthreads();
#pragma unroll
        for (int j = 0; j < 16; ++j) {
            const int row = j * 4 + rb;
            Wt[z * (Dv * Dv) + (n0 + row) * Dv + k0 + col] = f2bf(T[col][row]);
        }
        if (rem == 0) {
            biasStack[z * Dv + t]       = b[t];
            biasStack[z * Dv + t + 256] = b[t + 256];
        }
    }
}

// ---------------------------------------------------------------------------
// Fused Q/K/V projection GEMM, 128x64 tile, grid (8,32,3) = 768 blocks
// (exactly 3/CU -> no tail imbalance).  z=0: Q bf16 scaled 1/8; z=1: K bf16;
// z=2: V bf16 transposed per-batch [b][d][m].
// ---------------------------------------------------------------------------
__global__ __launch_bounds__(256) void qkv_gemm_kernel(
    const unsigned short* __restrict__ Ab, const unsigned short* __restrict__ Wt,
    const float* __restrict__ bst, unsigned short* __restrict__ Qb2,
    unsigned short* __restrict__ Kb2, unsigned short* __restrict__ Vt2)
{
    const int z = blockIdx.z;
    const unsigned short* A = Ab + (size_t)z * (MNv * Dv);
    const unsigned short* Wz = Wt + (size_t)z * (Dv * Dv);
    const float* bias = bst + z * Dv;

    const int n0 = blockIdx.x * 64;
    const int m0 = blockIdx.y * 128;
    const int t = threadIdx.x;
    const int w = t >> 6, lane = t & 63;
    const int wm = w & 1, wn = w >> 1;

    __shared__ unsigned short As[128][32];
    __shared__ unsigned short Bs[64][32];

    f32x4 acc[4][2] = {};

    const int sr = lane >> 2;
    const int sk = (lane & 3) * 8;
    const int fr = lane & 15;
    const int fk = (lane >> 4) * 8;

    for (int k0 = 0; k0 < Dv; k0 += 32) {
        __syncthreads();
#pragma unroll
        for (int j = 0; j < 2; ++j) {
            const int row = w * 32 + j * 16 + sr;
            gload_lds16(A + (size_t)(m0 + row) * Dv + k0 + sk, &As[w * 32 + j * 16][0]);
        }
        gload_lds16(Wz + (size_t)(n0 + w * 16 + sr) * Dv + k0 + sk, &Bs[w * 16][0]);
        __syncthreads();

        bf16x8 af[4], bfr[2];
#pragma unroll
        for (int mt = 0; mt < 4; ++mt)
            af[mt] = *(const bf16x8*)&As[wm * 64 + mt * 16 + fr][fk];
#pragma unroll
        for (int nt = 0; nt < 2; ++nt)
            bfr[nt] = *(const bf16x8*)&Bs[wn * 32 + nt * 16 + fr][fk];
#pragma unroll
        for (int mt = 0; mt < 4; ++mt)
#pragma unroll
            for (int nt = 0; nt < 2; ++nt)
                acc[mt][nt] = __builtin_amdgcn_mfma_f32_16x16x32_bf16(
                    af[mt], bfr[nt], acc[mt][nt], 0, 0, 0);
    }

    const int er = (lane >> 4) * 4;
    const int ec = lane & 15;
    const float scale = (z == 0) ? 0.125f : 1.0f;
#pragma unroll
    for (int nt = 0; nt < 2; ++nt) {
        const int gn = n0 + wn * 32 + nt * 16 + ec;
        const float bv_ = bias[gn];
#pragma unroll
        for (int mt = 0; mt < 4; ++mt) {
            const int gm = m0 + wm * 64 + mt * 16 + er;
            if (z == 2) {
                ushort4 o;
                o.x = f2bf(acc[mt][nt][0] + bv_);
                o.y = f2bf(acc[mt][nt][1] + bv_);
                o.z = f2bf(acc[mt][nt][2] + bv_);
                o.w = f2bf(acc[mt][nt][3] + bv_);
                *(ushort4*)(Vt2 + ((size_t)(gm >> 8) * Dv + gn) * Nv + (gm & 255)) = o;
            } else {
                unsigned short* cp = ((z == 0) ? Qb2 : Kb2) + (size_t)gm * Dv + gn;
#pragma unroll
                for (int r = 0; r < 4; ++r)
                    cp[(size_t)r * Dv] = f2bf((acc[mt][nt][r] + bv_) * scale);
            }
        }
    }
}

// ---------------------------------------------------------------------------
// Output GEMM: out[4096][512] = CTXb @ Wo^T + bias, fp32.  128x64 tile,
// grid (8,32) = 256 blocks (full GPU).
// ---------------------------------------------------------------------------
__global__ __launch_bounds__(256) void out_gemm_kernel(
    const unsigned short* __restrict__ A, const unsigned short* __restrict__ Wz,
    const float* __restrict__ bias, float* __restrict__ C)
{
    const int n0 = blockIdx.x * 64;
    const int m0 = blockIdx.y * 128;
    const int t = threadIdx.x;
    const int w = t >> 6, lane = t & 63;
    const int wm = w & 1, wn = w >> 1;

    __shared__ unsigned short As[128][32];
    __shared__ unsigned short Bs[64][32];

    f32x4 acc[4][2] = {};

    const int sr = lane >> 2;
    const int sk = (lane & 3) * 8;
    const int fr = lane & 15;
    const int fk = (lane >> 4) * 8;

    for (int k0 = 0; k0 < Dv; k0 += 32) {
        __syncthreads();
#pragma unroll
        for (int j = 0; j < 2; ++j) {
            const int row = w * 32 + j * 16 + sr;
            gload_lds16(A + (size_t)(m0 + row) * Dv + k0 + sk, &As[w * 32 + j * 16][0]);
        }
        gload_lds16(Wz + (size_t)(n0 + w * 16 + sr) * Dv + k0 + sk, &Bs[w * 16][0]);
        __syncthreads();

        bf16x8 af[4], bfr[2];
#pragma unroll
        for (int mt = 0; mt < 4; ++mt)
            af[mt] = *(const bf16x8*)&As[wm * 64 + mt * 16 + fr][fk];
#pragma unroll
        for (int nt = 0; nt < 2; ++nt)
            bfr[nt] = *(const bf16x8*)&Bs[wn * 32 + nt * 16 + fr][fk];
#pragma unroll
        for (int mt = 0; mt < 4; ++mt)
#pragma unroll
            for (int nt = 0; nt < 2; ++nt)
                acc[mt][nt] = __builtin_amdgcn_mfma_f32_16x16x32_bf16(
                    af[mt], bfr[nt], acc[mt][nt], 0, 0, 0);
    }

    const int er = (lane >> 4) * 4;
    const int ec = lane & 15;
#pragma unroll
    for (int nt = 0; nt < 2; ++nt) {
        const int gn = n0 + wn * 32 + nt * 16 + ec;
        const float bv_ = bias[gn];
#pragma unroll
        for (int mt = 0; mt < 4; ++mt) {
            const int gm = m0 + wm * 64 + mt * 16 + er;
            float* cp = C + (size_t)gm * Dv + gn;
#pragma unroll
            for (int r = 0; r < 4; ++r)
                cp[(size_t)r * Dv] = acc[mt][nt][r] + bv_;
        }
    }
}

// ---------------------------------------------------------------------------
// attn3 (MFMA): block=(64q, h, b), 4 waves; wave owns 16 q rows.
// LB (permuted) preloaded as MFMA C accumulator; Q pre-scaled 1/8.
// Softmax in registers; P -> LDS (aliasing dead K); PV vs V^T.
// LDS: Qs 9.2K + Ks/Pb 36.9K + Vt 33.8K = 78K -> 2 blocks/CU.
// ---------------------------------------------------------------------------
__global__ __launch_bounds__(256) void attn3_kernel(
    const unsigned short* __restrict__ Qb2, const unsigned short* __restrict__ Kb2,
    const unsigned short* __restrict__ Vt2, const __half* __restrict__ LB,
    unsigned short* __restrict__ CTXb)
{
    const int qt = blockIdx.x, h = blockIdx.y, b = blockIdx.z;
    const int q0 = qt * 64;
    const int t = threadIdx.x, w = t >> 6, lane = t & 63;
    const int fr = lane & 15, fq = lane >> 4;

    __shared__ unsigned short Qs[64][72];
    __shared__ unsigned short Ks[256][72];
    __shared__ unsigned short Vt[64][264];
    unsigned short (*Pb)[264] = (unsigned short (*)[264])&Ks[0][0];

#pragma unroll
    for (int i = 0; i < 2; ++i) {          // Q
        const int idx = t + i * 256;
        const int row = idx >> 3, cu = idx & 7;
        *(bf16x8*)&Qs[row][cu * 8] =
            *(const bf16x8*)(Qb2 + (size_t)(b * Nv + q0 + row) * Dv + h * 64 + cu * 8);
    }
#pragma unroll
    for (int i = 0; i < 8; ++i) {          // K
        const int idx = t + i * 256;
        const int row = idx >> 3, cu = idx & 7;
        *(bf16x8*)&Ks[row][cu * 8] =
            *(const bf16x8*)(Kb2 + (size_t)(b * Nv + row) * Dv + h * 64 + cu * 8);
    }
#pragma unroll
    for (int i = 0; i < 8; ++i) {          // V^T
        const int idx = t + i * 256;
        const int row = idx >> 5, cu = idx & 31;
        *(bf16x8*)&Vt[row][cu * 8] =
            *(const bf16x8*)(Vt2 + (size_t)b * (Dv * Nv) + (h * 64 + row) * Nv + cu * 8);
    }

    // ---- acc init from permuted LB: row q=qb+r, 16 contiguous halfs @ fr*16
    f32x4 acc[16];
    const int qb = q0 + w * 16 + fq * 4;
    const __half* lbp = LB + ((size_t)(b * Hv + h) * Nv + qb) * Nv + fr * 16;
#pragma unroll
    for (int r = 0; r < 4; ++r) {
        union { int4 v; __half hs[8]; } u0, u1;
        const int4* p = (const int4*)(lbp + (size_t)r * Nv);
        u0.v = p[0]; u1.v = p[1];
#pragma unroll
        for (int nt = 0; nt < 8; ++nt) acc[nt][r]     = __half2float(u0.hs[nt]);
#pragma unroll
        for (int nt = 0; nt < 8; ++nt) acc[nt + 8][r] = __half2float(u1.hs[nt]);
    }

    __syncthreads();

    // ---- QK^T ----
    const bf16x8 aq0 = *(const bf16x8*)&Qs[w * 16 + fr][fq * 8];
    const bf16x8 aq1 = *(const bf16x8*)&Qs[w * 16 + fr][32 + fq * 8];
#pragma unroll
    for (int nt = 0; nt < 16; ++nt) {
        const bf16x8 bk0 = *(const bf16x8*)&Ks[nt * 16 + fr][fq * 8];
        const bf16x8 bk1 = *(const bf16x8*)&Ks[nt * 16 + fr][32 + fq * 8];
        acc[nt] = __builtin_amdgcn_mfma_f32_16x16x32_bf16(aq0, bk0, acc[nt], 0, 0, 0);
        acc[nt] = __builtin_amdgcn_mfma_f32_16x16x32_bf16(aq1, bk1, acc[nt], 0, 0, 0);
    }

    // ---- softmax in registers ----
    float ri[4];
#pragma unroll
    for (int r = 0; r < 4; ++r) {
        float mx = acc[0][r];
#pragma unroll
        for (int nt = 1; nt < 16; ++nt) mx = fmaxf(mx, acc[nt][r]);
        mx = fmaxf(mx, __shfl_xor(mx, 1));
        mx = fmaxf(mx, __shfl_xor(mx, 2));
        mx = fmaxf(mx, __shfl_xor(mx, 4));
        mx = fmaxf(mx, __shfl_xor(mx, 8));
        float s = 0.0f;
#pragma unroll
        for (int nt = 0; nt < 16; ++nt) {
            const float e = __expf(acc[nt][r] - mx);
            acc[nt][r] = e;
            s += e;
        }
        s += __shfl_xor(s, 1);
        s += __shfl_xor(s, 2);
        s += __shfl_xor(s, 4);
        s += __shfl_xor(s, 8);
        ri[r] = 1.0f / s;
    }

    __syncthreads();   // all Ks reads complete before P overwrites the buffer

#pragma unroll
    for (int nt = 0; nt < 16; ++nt)
#pragma unroll
        for (int r = 0; r < 4; ++r)
            Pb[w * 16 + fq * 4 + r][nt * 16 + fr] = f2bf(acc[nt][r] * ri[r]);

    // ---- PV ----
    f32x4 o[4] = {};
#pragma unroll
    for (int kt = 0; kt < 8; ++kt) {
        const bf16x8 ap = *(const bf16x8*)&Pb[w * 16 + fr][kt * 32 + fq * 8];
#pragma unroll
        for (int nt2 = 0; nt2 < 4; ++nt2) {
            const bf16x8 bv_ = *(const bf16x8*)&Vt[nt2 * 16 + fr][kt * 32 + fq * 8];
            o[nt2] = __builtin_amdgcn_mfma_f32_16x16x32_bf16(ap, bv_, o[nt2], 0, 0, 0);
        }
    }

#pragma unroll
    for (int nt2 = 0; nt2 < 4; ++nt2)
#pragma unroll
        for (int r = 0; r < 4; ++r)
            CTXb[(size_t)(b * Nv + qb + r) * Dv + h * 64 + nt2 * 16 + fr] =
                f2bf(o[nt2][r]);
}

// ---------------------------------------------------------------------------
extern "C" void kernel_launch(void* const* d_in, const int* in_sizes, int n_in,
                              void* d_out, int out_size, void* d_ws, size_t ws_size,
                              hipStream_t stream) {
    (void)in_sizes; (void)n_in; (void)out_size; (void)ws_size;

    const float* inq  = (const float*)d_in[0];
    const float* ink  = (const float*)d_in[1];
    const float* inv  = (const float*)d_in[2];
    const float* box  = (const float*)d_in[3];
    const int*   mask = (const int*)d_in[4];
    const float* Wq   = (const float*)d_in[5];
    const float* bq   = (const float*)d_in[6];
    const float* Wk   = (const float*)d_in[7];
    const float* bk   = (const float*)d_in[8];
    const float* Wv   = (const float*)d_in[9];
    const float* bv   = (const float*)d_in[10];
    const float* Wo   = (const float*)d_in[11];
    const float* bo   = (const float*)d_in[12];
    const float* WGw  = (const float*)d_in[13];
    const float* WGb  = (const float*)d_in[14];

    char* W = (char*)d_ws;
    const size_t MB = 1048576;
    unsigned short* Qb2  = (unsigned short*)(W + 0);        // 4 MB bf16 [b][m][512], pre-scaled 1/8
    unsigned short* Kb2  = (unsigned short*)(W + 4 * MB);   // 4 MB bf16 [b][m][512]
    unsigned short* Vt2  = (unsigned short*)(W + 8 * MB);   // 4 MB bf16 [b][d][m]
    unsigned short* Wt   = (unsigned short*)(W + 12 * MB);  // 2 MB (4 transposed weights)
    float*          bst  = (float*)(W + 14 * MB);           // 8 KB bias stack
    unsigned short* CTXb = (unsigned short*)(W + 15 * MB);  // 4 MB
    unsigned short* Ab   = (unsigned short*)(W + 20 * MB);  // 12 MB (3 bf16 input planes)
    __half*         LB   = (__half*)(W + 32 * MB);          // 16.8 MB (no longer aliases Ab —
                                                            // geo now runs concurrently with conv)
    float* out = (float*)d_out;

    mega1_kernel<<<10496, 256, 0, stream>>>(
        box, mask, WGw, WGb, LB,
        inq, ink, inv, Ab,
        Wq, Wk, Wv, Wo, bq, bk, bv, bo, Wt, bst);

    qkv_gemm_kernel<<<dim3(8, 32, 3), 256, 0, stream>>>(Ab, Wt, bst, Qb2, Kb2, Vt2);

    attn3_kernel<<<dim3(4, 8, 16), 256, 0, stream>>>(Qb2, Kb2, Vt2, LB, CTXb);

    out_gemm_kernel<<<dim3(8, 32), 256, 0, stream>>>(CTXb, Wt + 3 * (Dv * Dv), bst + 3 * Dv, out);
}

// Round 11
// 159.037 us; speedup vs baseline: 1.1963x; 1.0130x over previous
//
#include <hip/hip_runtime.h>
#include <hip/hip_fp16.h>
#include <math.h>

#define Bv   16
#define Nv   256
#define Dv   512
#define Hv   8
#define MNv  4096          // B*N tokens

typedef __attribute__((ext_vector_type(8))) short bf16x8;
typedef __attribute__((ext_vector_type(4))) float f32x4;
typedef __fp16 fp16x8 __attribute__((ext_vector_type(8)));
typedef __fp16 fp16x2 __attribute__((ext_vector_type(2)));

__device__ __forceinline__ unsigned short f2bf(float f) {   // RNE
    unsigned u = __float_as_uint(f);
    u = u + 0x7FFFu + ((u >> 16) & 1u);
    return (unsigned short)(u >> 16);
}
__device__ __forceinline__ void gload_lds16(const void* g, void* l) {
    __builtin_amdgcn_global_load_lds(
        (const __attribute__((address_space(1))) unsigned int*)g,
        (__attribute__((address_space(3))) unsigned int*)l, 16, 0, 0);
}

// Raw HW transcendentals (the OCML wrappers are ~30-80 instr precise routines;
// v_sin/v_cos/v_log/v_exp/v_rcp are single trans-unit ops).
__device__ __forceinline__ void fast_sincos(float x, float* s, float* c) {
    const float rev = x * 0.15915494309189535f;   // 1/(2*pi); v_sin takes revolutions
    const float fr  = rev - floorf(rev);
    *s = __builtin_amdgcn_sinf(fr);
    *c = __builtin_amdgcn_cosf(fr);
}
__device__ __forceinline__ float fast_log(float x) {        // ln(x) via v_log_f32
    return __builtin_amdgcn_logf(x) * 0.6931471805599453f;
}
__device__ __forceinline__ float fast_exp(float x) {        // e^x via v_exp_f32
    return __builtin_amdgcn_exp2f(x * 1.4426950408889634f);
}

// ---------------------------------------------------------------------------
// MEGA-1: geo-bias (blocks 0..4095) + fp32->bf16 input conv (4096..10239)
// + weight transpose conv (10240..10495), one launch.
// ---------------------------------------------------------------------------
__global__ __launch_bounds__(256) void mega1_kernel(
    const float* __restrict__ box, const int* __restrict__ mask,
    const float* __restrict__ WGw, const float* __restrict__ WGb,
    __half* __restrict__ LB,
    const float* __restrict__ xq, const float* __restrict__ xk,
    const float* __restrict__ xv, unsigned short* __restrict__ Ab,
    const float* __restrict__ Wq, const float* __restrict__ Wk,
    const float* __restrict__ Wv, const float* __restrict__ Wo,
    const float* __restrict__ bq, const float* __restrict__ bk,
    const float* __restrict__ bv, const float* __restrict__ bo,
    unsigned short* __restrict__ Wt, float* __restrict__ biasStack)
{
    __shared__ __align__(16) char smraw[64 * 65 * 4];   // union: geo Lst / conv_w T
    const int bid = blockIdx.x;
    const int t = threadIdx.x;

    if (bid < 4096) {
        // ================= geo-bias =================
        unsigned short (*Lst)[264] = (unsigned short (*)[264])smraw;
        const int q = bid & 255;
        const int b = bid >> 8;
        const int w = t >> 6, lane = t & 63;
        const int n = lane & 15;
        const int quad = lane >> 4;

        const float4 bq_ = *(const float4*)(box + (b * Nv + q) * 4);
        const float cxq = (bq_.x + bq_.z) * 0.5f;
        const float cyq = (bq_.y + bq_.w) * 0.5f;
        const float wq  = bq_.z - bq_.x + 1.0f;
        const float hq  = bq_.w - bq_.y + 1.0f;

        union F16x8 { fp16x8 v; fp16x2 p[4]; };
        F16x8 Bs_, Bc_;
        Bs_.v = (fp16x8){}; Bc_.v = (fp16x8){};
        float bias_n = 0.0f;
        if (n < Hv) {
            bias_n = WGb[n];
#pragma unroll
            for (int jj = 0; jj < 4; ++jj) {
                Bs_.p[jj] = __builtin_amdgcn_cvt_pkrtz(WGw[n * 64 + quad * 8 + 2 * jj],
                                                       WGw[n * 64 + quad * 8 + 2 * jj + 1]);
                Bc_.p[jj] = __builtin_amdgcn_cvt_pkrtz(WGw[n * 64 + 32 + quad * 8 + 2 * jj],
                                                       WGw[n * 64 + 32 + quad * 8 + 2 * jj + 1]);
            }
        }

        const float dimm[8] = {1.0f, 0.42169650342f, 0.17782794100f, 0.07498942093f,
                               0.03162277660f, 0.01333521432f, 0.00562341325f, 0.00237137371f};
        const bool isCtr = (quad < 2);
        const bool isY   = (quad & 1);
        const float cq  = isY ? cyq : cxq;
        const float sq_ = isY ? hq : wq;

#pragma unroll
        for (int i = 0; i < 4; ++i) {
            const int m0 = (w * 4 + i) * 16;
            const float4 bm = *(const float4*)(box + (b * Nv + m0 + n) * 4);
            const float cxm = (bm.x + bm.z) * 0.5f;
            const float cym = (bm.y + bm.w) * 0.5f;
            const float wm  = bm.z - bm.x + 1.0f;
            const float hm  = bm.w - bm.y + 1.0f;
            const float cm_ = isY ? cym : cxm;
            const float sm_ = isY ? hm : wm;
            const float top = isCtr ? fabsf(cq - cm_) : sq_;
            const float bot = isCtr ? sq_ : sm_;
            float r = top * __builtin_amdgcn_rcpf(bot);
            if (isCtr) r = fmaxf(r, 1e-3f);
            // 100 * ln(r) = 100*ln2 * log2(r)
            const float base = 69.31471805599453f * __builtin_amdgcn_logf(r);

            float sv[8], cv[8];
#pragma unroll
            for (int j = 0; j < 8; ++j)
                fast_sincos(base * dimm[j], &sv[j], &cv[j]);

            F16x8 As_, Ac_;
#pragma unroll
            for (int jj = 0; jj < 4; ++jj) {
                As_.p[jj] = __builtin_amdgcn_cvt_pkrtz(sv[2 * jj], sv[2 * jj + 1]);
                Ac_.p[jj] = __builtin_amdgcn_cvt_pkrtz(cv[2 * jj], cv[2 * jj + 1]);
            }

            f32x4 acc = {};
            acc = __builtin_amdgcn_mfma_f32_16x16x32_f16(As_.v, Bs_.v, acc, 0, 0, 0);
            acc = __builtin_amdgcn_mfma_f32_16x16x32_f16(Ac_.v, Bc_.v, acc, 0, 0, 0);

            const int mrow = m0 + quad * 4;
            const int4 mk = *(const int4*)(mask + b * Nv + mrow);
            if (n < Hv) {
                const int* mkp = (const int*)&mk;
                const int pos0 = quad * 64 + (w * 4 + i);
#pragma unroll
                for (int rr = 0; rr < 4; ++rr) {
                    const float val = fmaxf(acc[rr] + bias_n, 1e-6f);
                    const float lb = fast_log(val) + (mkp[rr] ? 0.0f : -30000.0f);
                    Lst[n][pos0 + rr * 16] = __half_as_ushort(__float2half(lb));
                }
            }
        }

        __syncthreads();
        const int h = t >> 5, c = t & 31;
        unsigned short* dst = (unsigned short*)LB +
                              ((size_t)(b * Hv + h) * Nv + q) * Nv + c * 8;
        *(int4*)dst = *(const int4*)&Lst[h][c * 8];

    } else if (bid < 10240) {
        // ================= input fp32 -> bf16 =================
        const int i = bid - 4096;
        const int z = i >> 11;            // 0..2
        const int xblk = i & 2047;
        const float* src = (z == 0) ? xq : (z == 1) ? xk : xv;
        const size_t base = (size_t)z * (MNv * Dv);
        const int idx = (xblk * 256 + t) * 4;
        float4 x = *(const float4*)(src + idx);
        ushort4 h4;
        h4.x = f2bf(x.x); h4.y = f2bf(x.y); h4.z = f2bf(x.z); h4.w = f2bf(x.w);
        *(ushort4*)(Ab + base + idx) = h4;

    } else {
        // ================= weight transpose (fp32 W[k][n] -> bf16 Wt[n][k]) =====
        float (*T)[65] = (float (*)[65])smraw;
        const int i = bid - 10240;        // 0..255
        const int z = i >> 6;
        const int rem = i & 63;
        const int n0 = (rem & 7) * 64, k0 = (rem >> 3) * 64;
        const float* W = (z == 0) ? Wq : (z == 1) ? Wk : (z == 2) ? Wv : Wo;
        const float* b = (z == 0) ? bq : (z == 1) ? bk : (z == 2) ? bv : bo;
        const int col = t & 63, rb = t >> 6;
#pragma unroll
        for (int j = 0; j < 16; ++j) {
            const int row = j * 4 + rb;
            T[row][col] = W[(k0 + row) * Dv + n0 + col];
        }
        __syncthreads();
#pragma unroll
        for (int j = 0; j < 16; ++j) {
            const int row = j * 4 + rb;
            Wt[z * (Dv * Dv) + (n0 + row) * Dv + k0 + col] = f2bf(T[col][row]);
        }
        if (rem == 0) {
            biasStack[z * Dv + t]       = b[t];
            biasStack[z * Dv + t + 256] = b[t + 256];
        }
    }
}

// ---------------------------------------------------------------------------
// Fused Q/K/V projection GEMM, 128x64 tile, grid (8,32,3) = 768 blocks.
// z=0: Q bf16 scaled 1/8; z=1: K bf16; z=2: V bf16 transposed [b][d][m].
// ---------------------------------------------------------------------------
__global__ __launch_bounds__(256) void qkv_gemm_kernel(
    const unsigned short* __restrict__ Ab, const unsigned short* __restrict__ Wt,
    const float* __restrict__ bst, unsigned short* __restrict__ Qb2,
    unsigned short* __restrict__ Kb2, unsigned short* __restrict__ Vt2)
{
    const int z = blockIdx.z;
    const unsigned short* A = Ab + (size_t)z * (MNv * Dv);
    const unsigned short* Wz = Wt + (size_t)z * (Dv * Dv);
    const float* bias = bst + z * Dv;

    const int n0 = blockIdx.x * 64;
    const int m0 = blockIdx.y * 128;
    const int t = threadIdx.x;
    const int w = t >> 6, lane = t & 63;
    const int wm = w & 1, wn = w >> 1;

    __shared__ unsigned short As[128][32];
    __shared__ unsigned short Bs[64][32];

    f32x4 acc[4][2] = {};

    const int sr = lane >> 2;
    const int sk = (lane & 3) * 8;
    const int fr = lane & 15;
    const int fk = (lane >> 4) * 8;

    for (int k0 = 0; k0 < Dv; k0 += 32) {
        __syncthreads();
#pragma unroll
        for (int j = 0; j < 2; ++j) {
            const int row = w * 32 + j * 16 + sr;
            gload_lds16(A + (size_t)(m0 + row) * Dv + k0 + sk, &As[w * 32 + j * 16][0]);
        }
        gload_lds16(Wz + (size_t)(n0 + w * 16 + sr) * Dv + k0 + sk, &Bs[w * 16][0]);
        __syncthreads();

        bf16x8 af[4], bfr[2];
#pragma unroll
        for (int mt = 0; mt < 4; ++mt)
            af[mt] = *(const bf16x8*)&As[wm * 64 + mt * 16 + fr][fk];
#pragma unroll
        for (int nt = 0; nt < 2; ++nt)
            bfr[nt] = *(const bf16x8*)&Bs[wn * 32 + nt * 16 + fr][fk];
#pragma unroll
        for (int mt = 0; mt < 4; ++mt)
#pragma unroll
            for (int nt = 0; nt < 2; ++nt)
                acc[mt][nt] = __builtin_amdgcn_mfma_f32_16x16x32_bf16(
                    af[mt], bfr[nt], acc[mt][nt], 0, 0, 0);
    }

    const int er = (lane >> 4) * 4;
    const int ec = lane & 15;
    const float scale = (z == 0) ? 0.125f : 1.0f;
#pragma unroll
    for (int nt = 0; nt < 2; ++nt) {
        const int gn = n0 + wn * 32 + nt * 16 + ec;
        const float bv_ = bias[gn];
#pragma unroll
        for (int mt = 0; mt < 4; ++mt) {
            const int gm = m0 + wm * 64 + mt * 16 + er;
            if (z == 2) {
                ushort4 o;
                o.x = f2bf(acc[mt][nt][0] + bv_);
                o.y = f2bf(acc[mt][nt][1] + bv_);
                o.z = f2bf(acc[mt][nt][2] + bv_);
                o.w = f2bf(acc[mt][nt][3] + bv_);
                *(ushort4*)(Vt2 + ((size_t)(gm >> 8) * Dv + gn) * Nv + (gm & 255)) = o;
            } else {
                unsigned short* cp = ((z == 0) ? Qb2 : Kb2) + (size_t)gm * Dv + gn;
#pragma unroll
                for (int r = 0; r < 4; ++r)
                    cp[(size_t)r * Dv] = f2bf((acc[mt][nt][r] + bv_) * scale);
            }
        }
    }
}

// ---------------------------------------------------------------------------
// Output GEMM: out[4096][512] = CTXb @ Wo^T + bias, fp32.  128x64 tile,
// grid (8,32) = 256 blocks.
// ---------------------------------------------------------------------------
__global__ __launch_bounds__(256) void out_gemm_kernel(
    const unsigned short* __restrict__ A, const unsigned short* __restrict__ Wz,
    const float* __restrict__ bias, float* __restrict__ C)
{
    const int n0 = blockIdx.x * 64;
    const int m0 = blockIdx.y * 128;
    const int t = threadIdx.x;
    const int w = t >> 6, lane = t & 63;
    const int wm = w & 1, wn = w >> 1;

    __shared__ unsigned short As[128][32];
    __shared__ unsigned short Bs[64][32];

    f32x4 acc[4][2] = {};

    const int sr = lane >> 2;
    const int sk = (lane & 3) * 8;
    const int fr = lane & 15;
    const int fk = (lane >> 4) * 8;

    for (int k0 = 0; k0 < Dv; k0 += 32) {
        __syncthreads();
#pragma unroll
        for (int j = 0; j < 2; ++j) {
            const int row = w * 32 + j * 16 + sr;
            gload_lds16(A + (size_t)(m0 + row) * Dv + k0 + sk, &As[w * 32 + j * 16][0]);
        }
        gload_lds16(Wz + (size_t)(n0 + w * 16 + sr) * Dv + k0 + sk, &Bs[w * 16][0]);
        __syncthreads();

        bf16x8 af[4], bfr[2];
#pragma unroll
        for (int mt = 0; mt < 4; ++mt)
            af[mt] = *(const bf16x8*)&As[wm * 64 + mt * 16 + fr][fk];
#pragma unroll
        for (int nt = 0; nt < 2; ++nt)
            bfr[nt] = *(const bf16x8*)&Bs[wn * 32 + nt * 16 + fr][fk];
#pragma unroll
        for (int mt = 0; mt < 4; ++mt)
#pragma unroll
            for (int nt = 0; nt < 2; ++nt)
                acc[mt][nt] = __builtin_amdgcn_mfma_f32_16x16x32_bf16(
                    af[mt], bfr[nt], acc[mt][nt], 0, 0, 0);
    }

    const int er = (lane >> 4) * 4;
    const int ec = lane & 15;
#pragma unroll
    for (int nt = 0; nt < 2; ++nt) {
        const int gn = n0 + wn * 32 + nt * 16 + ec;
        const float bv_ = bias[gn];
#pragma unroll
        for (int mt = 0; mt < 4; ++mt) {
            const int gm = m0 + wm * 64 + mt * 16 + er;
            float* cp = C + (size_t)gm * Dv + gn;
#pragma unroll
            for (int r = 0; r < 4; ++r)
                cp[(size_t)r * Dv] = acc[mt][nt][r] + bv_;
        }
    }
}

// ---------------------------------------------------------------------------
// attn3 (MFMA): block=(64q, h, b), 4 waves; wave owns 16 q rows.
// LB (permuted) preloaded as MFMA C accumulator; Q pre-scaled 1/8.
// Softmax in registers (HW v_exp/v_rcp); P -> LDS (aliasing dead K); PV vs V^T.
// ---------------------------------------------------------------------------
__global__ __launch_bounds__(256) void attn3_kernel(
    const unsigned short* __restrict__ Qb2, const unsigned short* __restrict__ Kb2,
    const unsigned short* __restrict__ Vt2, const __half* __restrict__ LB,
    unsigned short* __restrict__ CTXb)
{
    const int qt = blockIdx.x, h = blockIdx.y, b = blockIdx.z;
    const int q0 = qt * 64;
    const int t = threadIdx.x, w = t >> 6, lane = t & 63;
    const int fr = lane & 15, fq = lane >> 4;

    __shared__ unsigned short Qs[64][72];
    __shared__ unsigned short Ks[256][72];
    __shared__ unsigned short Vt[64][264];
    unsigned short (*Pb)[264] = (unsigned short (*)[264])&Ks[0][0];

#pragma unroll
    for (int i = 0; i < 2; ++i) {          // Q
        const int idx = t + i * 256;
        const int row = idx >> 3, cu = idx & 7;
        *(bf16x8*)&Qs[row][cu * 8] =
            *(const bf16x8*)(Qb2 + (size_t)(b * Nv + q0 + row) * Dv + h * 64 + cu * 8);
    }
#pragma unroll
    for (int i = 0; i < 8; ++i) {          // K
        const int idx = t + i * 256;
        const int row = idx >> 3, cu = idx & 7;
        *(bf16x8*)&Ks[row][cu * 8] =
            *(const bf16x8*)(Kb2 + (size_t)(b * Nv + row) * Dv + h * 64 + cu * 8);
    }
#pragma unroll
    for (int i = 0; i < 8; ++i) {          // V^T
        const int idx = t + i * 256;
        const int row = idx >> 5, cu = idx & 31;
        *(bf16x8*)&Vt[row][cu * 8] =
            *(const bf16x8*)(Vt2 + (size_t)b * (Dv * Nv) + (h * 64 + row) * Nv + cu * 8);
    }

    // ---- acc init from permuted LB: row q=qb+r, 16 contiguous halfs @ fr*16
    f32x4 acc[16];
    const int qb = q0 + w * 16 + fq * 4;
    const __half* lbp = LB + ((size_t)(b * Hv + h) * Nv + qb) * Nv + fr * 16;
#pragma unroll
    for (int r = 0; r < 4; ++r) {
        union { int4 v; __half hs[8]; } u0, u1;
        const int4* p = (const int4*)(lbp + (size_t)r * Nv);
        u0.v = p[0]; u1.v = p[1];
#pragma unroll
        for (int nt = 0; nt < 8; ++nt) acc[nt][r]     = __half2float(u0.hs[nt]);
#pragma unroll
        for (int nt = 0; nt < 8; ++nt) acc[nt + 8][r] = __half2float(u1.hs[nt]);
    }

    __syncthreads();

    // ---- QK^T ----
    const bf16x8 aq0 = *(const bf16x8*)&Qs[w * 16 + fr][fq * 8];
    const bf16x8 aq1 = *(const bf16x8*)&Qs[w * 16 + fr][32 + fq * 8];
#pragma unroll
    for (int nt = 0; nt < 16; ++nt) {
        const bf16x8 bk0 = *(const bf16x8*)&Ks[nt * 16 + fr][fq * 8];
        const bf16x8 bk1 = *(const bf16x8*)&Ks[nt * 16 + fr][32 + fq * 8];
        acc[nt] = __builtin_amdgcn_mfma_f32_16x16x32_bf16(aq0, bk0, acc[nt], 0, 0, 0);
        acc[nt] = __builtin_amdgcn_mfma_f32_16x16x32_bf16(aq1, bk1, acc[nt], 0, 0, 0);
    }

    // ---- softmax in registers (HW exp2/rcp) ----
    float ri[4];
#pragma unroll
    for (int r = 0; r < 4; ++r) {
        float mx = acc[0][r];
#pragma unroll
        for (int nt = 1; nt < 16; ++nt) mx = fmaxf(mx, acc[nt][r]);
        mx = fmaxf(mx, __shfl_xor(mx, 1));
        mx = fmaxf(mx, __shfl_xor(mx, 2));
        mx = fmaxf(mx, __shfl_xor(mx, 4));
        mx = fmaxf(mx, __shfl_xor(mx, 8));
        float s = 0.0f;
#pragma unroll
        for (int nt = 0; nt < 16; ++nt) {
            const float e = fast_exp(acc[nt][r] - mx);
            acc[nt][r] = e;
            s += e;
        }
        s += __shfl_xor(s, 1);
        s += __shfl_xor(s, 2);
        s += __shfl_xor(s, 4);
        s += __shfl_xor(s, 8);
        ri[r] = __builtin_amdgcn_rcpf(s);
    }

    __syncthreads();   // all Ks reads complete before P overwrites the buffer

#pragma unroll
    for (int nt = 0; nt < 16; ++nt)
#pragma unroll
        for (int r = 0; r < 4; ++r)
            Pb[w * 16 + fq * 4 + r][nt * 16 + fr] = f2bf(acc[nt][r] * ri[r]);

    // ---- PV ----
    f32x4 o[4] = {};
#pragma unroll
    for (int kt = 0; kt < 8; ++kt) {
        const bf16x8 ap = *(const bf16x8*)&Pb[w * 16 + fr][kt * 32 + fq * 8];
#pragma unroll
        for (int nt2 = 0; nt2 < 4; ++nt2) {
            const bf16x8 bv_ = *(const bf16x8*)&Vt[nt2 * 16 + fr][kt * 32 + fq * 8];
            o[nt2] = __builtin_amdgcn_mfma_f32_16x16x32_bf16(ap, bv_, o[nt2], 0, 0, 0);
        }
    }

#pragma unroll
    for (int nt2 = 0; nt2 < 4; ++nt2)
#pragma unroll
        for (int r = 0; r < 4; ++r)
            CTXb[(size_t)(b * Nv + qb + r) * Dv + h * 64 + nt2 * 16 + fr] =
                f2bf(o[nt2][r]);
}

// ---------------------------------------------------------------------------
extern "C" void kernel_launch(void* const* d_in, const int* in_sizes, int n_in,
                              void* d_out, int out_size, void* d_ws, size_t ws_size,
                              hipStream_t stream) {
    (void)in_sizes; (void)n_in; (void)out_size; (void)ws_size;

    const float* inq  = (const float*)d_in[0];
    const float* ink  = (const float*)d_in[1];
    const float* inv  = (const float*)d_in[2];
    const float* box  = (const float*)d_in[3];
    const int*   mask = (const int*)d_in[4];
    const float* Wq   = (const float*)d_in[5];
    const float* bq   = (const float*)d_in[6];
    const float* Wk   = (const float*)d_in[7];
    const float* bk   = (const float*)d_in[8];
    const float* Wv   = (const float*)d_in[9];
    const float* bv   = (const float*)d_in[10];
    const float* Wo   = (const float*)d_in[11];
    const float* bo   = (const float*)d_in[12];
    const float* WGw  = (const float*)d_in[13];
    const float* WGb  = (const float*)d_in[14];

    char* W = (char*)d_ws;
    const size_t MB = 1048576;
    unsigned short* Qb2  = (unsigned short*)(W + 0);        // 4 MB bf16 [b][m][512], pre-scaled 1/8
    unsigned short* Kb2  = (unsigned short*)(W + 4 * MB);   // 4 MB bf16 [b][m][512]
    unsigned short* Vt2  = (unsigned short*)(W + 8 * MB);   // 4 MB bf16 [b][d][m]
    unsigned short* Wt   = (unsigned short*)(W + 12 * MB);  // 2 MB (4 transposed weights)
    float*          bst  = (float*)(W + 14 * MB);           // 8 KB bias stack
    unsigned short* CTXb = (unsigned short*)(W + 15 * MB);  // 4 MB
    unsigned short* Ab   = (unsigned short*)(W + 20 * MB);  // 12 MB (3 bf16 input planes)
    __half*         LB   = (__half*)(W + 32 * MB);          // 16.8 MB

    float* out = (float*)d_out;

    mega1_kernel<<<10496, 256, 0, stream>>>(
        box, mask, WGw, WGb, LB,
        inq, ink, inv, Ab,
        Wq, Wk, Wv, Wo, bq, bk, bv, bo, Wt, bst);

    qkv_gemm_kernel<<<dim3(8, 32, 3), 256, 0, stream>>>(Ab, Wt, bst, Qb2, Kb2, Vt2);

    attn3_kernel<<<dim3(4, 8, 16), 256, 0, stream>>>(Qb2, Kb2, Vt2, LB, CTXb);

    out_gemm_kernel<<<dim3(8, 32), 256, 0, stream>>>(CTXb, Wt + 3 * (Dv * Dv), bst + 3 * Dv, out);
}